// Round 3
// baseline (728.517 us; speedup 1.0000x reference)
//
#include <hip/hip_runtime.h>
#include <stdint.h>

#define BATCH 4096
#define NEXP 64

typedef __bf16 bf16x8 __attribute__((ext_vector_type(8)));
typedef float f32x4 __attribute__((ext_vector_type(4)));
typedef unsigned int u32x4 __attribute__((ext_vector_type(4)));
typedef unsigned short u16x4 __attribute__((ext_vector_type(4)));
typedef unsigned short u16x8 __attribute__((ext_vector_type(8)));

__device__ __forceinline__ unsigned short f2bf(float f) {
  unsigned u = __builtin_bit_cast(unsigned, f);
  u += 0x7fffu + ((u >> 16) & 1u);
  return (unsigned short)(u >> 16);
}
__device__ __forceinline__ float bf2f(unsigned short h) {
  unsigned u = ((unsigned)h) << 16;
  return __builtin_bit_cast(float, u);
}

// async global->LDS, 16B per lane. LDS dest = wave-uniform base + lane*16.
__device__ __forceinline__ void async_copy16(const void* g, void* l) {
  __builtin_amdgcn_global_load_lds(
      (const __attribute__((address_space(1))) void*)(uintptr_t)g,
      (__attribute__((address_space(3))) void*)(uintptr_t)l, 16, 0, 0);
}

enum { AM_PLAIN = 0, AM_BN = 1, AM_EXPERT = 2 };

// ---------------------------------------------------------------------------
// Generic MFMA GEMM: C_slice[b,n] = sum_k A(b,k) * PB(k,n)  (+ bias[n])
//   B (PB) fragment-major packed bf16 (MFMA B-operand layout).
//   A built on the fly; staged to LDS with consecutive-tid -> consecutive
//   16B chunks (round-3 fix: old mapping had lanes at 256B stride -> ~16-way
//   bank conflicts, 1.47e7 SQ_LDS_BANK_CONFLICT per dispatch).
// ---------------------------------------------------------------------------
template <int BN_, int WR, int WC, int AMODE>
__global__ __launch_bounds__(256, 2) void gemm_k(
    const float* __restrict__ Af32, const float* __restrict__ scv,
    const float* __restrict__ shv, const float* __restrict__ alphaPtr,
    const unsigned short* __restrict__ zbf, const float* __restrict__ wmat,
    const float* __restrict__ invPtr, int shI, int EI,
    const unsigned short* __restrict__ PB, int K, int nsubsTot,
    float* __restrict__ Cbase, long partStride,
    const float* __restrict__ biasv, int N, int ktilesTot, int splits) {
  constexpr int BM = 128, BK = 64;
  constexpr int MS = BM / 16;   // A subtiles (8)
  constexpr int NS = BN_ / 16;  // B subtiles per block
  constexpr int WTM = BM / WR, WTN = BN_ / WC;
  constexpr int TM = WTM / 16, TN = WTN / 16;
  static_assert(BN_ == 64 || BN_ == 128, "");

  __shared__ __align__(16) unsigned short As[2 * MS * 512];
  __shared__ __align__(16) unsigned short Bs[2 * NS * 512];

  const int tid = threadIdx.x;
  const int lane = tid & 63;
  const int wid = tid >> 6;
  const int wrow = wid / WC, wcol = wid % WC;

  const int m0 = blockIdx.x * BM;
  const int ntile = blockIdx.y;
  const int n0 = ntile * BN_;
  const int slice = blockIdx.z;
  const int kt0 = (int)((long)slice * ktilesTot / splits);
  const int kt1 = (int)((long)(slice + 1) * ktilesTot / splits);

  float* __restrict__ Cp = Cbase + (long)slice * partStride;

  float alpha = 0.f, inv = 0.f;
  if constexpr (AMODE == AM_BN) alpha = alphaPtr[0];
  if constexpr (AMODE == AM_EXPERT) inv = invPtr[0];

  f32x4 acc[TM][TN] = {};

  for (int kt = kt0; kt < kt1; ++kt) {
    const int k0 = kt * BK;

    // ---- stage B: 2*NS fragments of 1KB, one wave-instruction each
    for (int f = wid; f < 2 * NS; f += 4) {
      const int fkt = f / NS, fns = f % NS;
      const long fragIdx = (long)(k0 / 32 + fkt) * nsubsTot + (ntile * NS + fns);
      async_copy16(PB + fragIdx * 512 + lane * 8, &Bs[f * 512 + lane * 8]);
    }

    // ---- stage A: 1024 16B chunks (128 rows x 8 k-chunks); thread writes 4;
    //      chunk id = p*256 + tid so lanes write consecutive 16B (no conflicts)
#pragma unroll
    for (int p = 0; p < 4; ++p) {
      const int id = p * 256 + tid;
      const int fA = id >> 6;          // fragment = ksh*8 + msub
      const int q = id & 63;           // chunk within fragment
      const int ksh = fA >> 3, msub = fA & 7;
      const int kq = q >> 4, mrow = q & 15;
      const int m = msub * 16 + mrow;
      const int kg = k0 + ksh * 32 + kq * 8;
      const long mg = m0 + m;
      float vals[8];
      if constexpr (AMODE == AM_PLAIN) {
        const f32x4* src = (const f32x4*)(Af32 + mg * K + kg);
        f32x4 a0 = src[0], a1 = src[1];
#pragma unroll
        for (int j = 0; j < 4; ++j) { vals[j] = a0[j]; vals[4 + j] = a1[j]; }
      } else if constexpr (AMODE == AM_BN) {
        const f32x4* src = (const f32x4*)(Af32 + mg * K + kg);
        f32x4 a0 = src[0], a1 = src[1];
        f32x4 s0 = *(const f32x4*)(scv + kg), s1 = *(const f32x4*)(scv + kg + 4);
        f32x4 h0 = *(const f32x4*)(shv + kg), h1 = *(const f32x4*)(shv + kg + 4);
#pragma unroll
        for (int j = 0; j < 4; ++j) {
          float v = fmaf(a0[j], s0[j], h0[j]);
          vals[j] = v >= 0.f ? v : alpha * v;
          float v2 = fmaf(a1[j], s1[j], h1[j]);
          vals[4 + j] = v2 >= 0.f ? v2 : alpha * v2;
        }
      } else {  // AM_EXPERT
        if (kg >= EI) {  // folded-bias region: A = wn[b, kg-EI]
          const f32x4* wr_ = (const f32x4*)(wmat + mg * NEXP + (kg - EI));
          f32x4 w0 = wr_[0], w1 = wr_[1];
#pragma unroll
          for (int j = 0; j < 4; ++j) {
            vals[j] = w0[j] * inv;
            vals[4 + j] = w1[j] * inv;
          }
        } else {  // A = wn[b,e] * z[b,i]
          const int e = kg >> shI;
          const int i0 = kg & ((1 << shI) - 1);
          const float wv = wmat[mg * NEXP + e] * inv;
          u16x8 zz = *(const u16x8*)(zbf + (mg << shI) + i0);
#pragma unroll
          for (int j = 0; j < 8; ++j) vals[j] = wv * bf2f(zz[j]);
        }
      }
      u16x8 ob;
#pragma unroll
      for (int j = 0; j < 8; ++j) ob[j] = f2bf(vals[j]);
      *(u16x8*)&As[id * 8] = ob;  // byte addr = id*16
    }
    __syncthreads();

    // ---- MFMA
#pragma unroll
    for (int ks = 0; ks < 2; ++ks) {
      bf16x8 af[TM], bfr[TN];
#pragma unroll
      for (int i = 0; i < TM; ++i) {
        const int msub = wrow * TM + i;
        af[i] = __builtin_bit_cast(
            bf16x8, *(const u32x4*)&As[(ks * MS + msub) * 512 + lane * 8]);
      }
#pragma unroll
      for (int j = 0; j < TN; ++j) {
        const int nsub = wcol * TN + j;
        bfr[j] = __builtin_bit_cast(
            bf16x8, *(const u32x4*)&Bs[(ks * NS + nsub) * 512 + lane * 8]);
      }
#pragma unroll
      for (int i = 0; i < TM; ++i)
#pragma unroll
        for (int j = 0; j < TN; ++j)
          acc[i][j] = __builtin_amdgcn_mfma_f32_16x16x32_bf16(af[i], bfr[j],
                                                              acc[i][j], 0, 0, 0);
    }
    __syncthreads();
  }

  // ---- epilogue: C/D layout col=lane&15, row=(lane>>4)*4+reg
  const int q = lane >> 4, nn = lane & 15;
#pragma unroll
  for (int i = 0; i < TM; ++i) {
    const int rowb = m0 + wrow * WTM + i * 16 + q * 4;
#pragma unroll
    for (int j = 0; j < TN; ++j) {
      const int col = n0 + wcol * WTN + j * 16 + nn;
      const float bv = biasv ? biasv[col] : 0.f;
#pragma unroll
      for (int r = 0; r < 4; ++r)
        Cp[(long)(rowb + r) * N + col] = acc[i][j][r] + bv;
    }
  }
}

// ---------------------------------------------------------------------------
// BN stats: 4 columns per block, float4 row reads (coalescing fix).
// Emits sc=g*rsqrt(var+eps), sh=b-mu*sc  (biased var, eps=1e-5)
// ---------------------------------------------------------------------------
__global__ void stats_k(const float* __restrict__ H, long partStride, int nparts,
                        int C, const float* __restrict__ g,
                        const float* __restrict__ b, float* __restrict__ scv,
                        float* __restrict__ shv) {
  const int c0 = blockIdx.x * 4;
  f32x4 s = {0.f, 0.f, 0.f, 0.f}, s2 = {0.f, 0.f, 0.f, 0.f};
  for (int r = threadIdx.x; r < BATCH; r += 256) {
    f32x4 x = {0.f, 0.f, 0.f, 0.f};
    for (int p = 0; p < nparts; ++p)
      x += *(const f32x4*)(H + p * partStride + (long)r * C + c0);
    s += x;
    s2 += x * x;
  }
  __shared__ f32x4 sb[256], qb[256];
  sb[threadIdx.x] = s;
  qb[threadIdx.x] = s2;
  __syncthreads();
  for (int st = 128; st > 0; st >>= 1) {
    if (threadIdx.x < st) {
      sb[threadIdx.x] += sb[threadIdx.x + st];
      qb[threadIdx.x] += qb[threadIdx.x + st];
    }
    __syncthreads();
  }
  if (threadIdx.x < 4) {
    const int c = c0 + threadIdx.x;
    float mu = sb[0][threadIdx.x] * (1.f / BATCH);
    float var = qb[0][threadIdx.x] * (1.f / BATCH) - mu * mu;
    float isig = 1.f / sqrtf(var + 1e-5f);
    float sc_ = g[c] * isig;
    scv[c] = sc_;
    shv[c] = b[c] - mu * sc_;
  }
}

// z = bf16(prelu(sc*sum(Hparts)+sh))
__global__ void zbuild_k(const float* __restrict__ H, long partStride, int nparts,
                         const float* __restrict__ scv,
                         const float* __restrict__ shv,
                         const float* __restrict__ alphaPtr,
                         unsigned short* __restrict__ z, int C, int total4) {
  const int idx = blockIdx.x * 256 + threadIdx.x;
  if (idx >= total4) return;
  const float alpha = alphaPtr[0];
  const int c0 = (idx * 4) & (C - 1);
  f32x4 x = {0.f, 0.f, 0.f, 0.f};
  for (int p = 0; p < nparts; ++p) x += *(const f32x4*)(H + p * partStride + (long)idx * 4);
  f32x4 sv = *(const f32x4*)(scv + c0);
  f32x4 hv = *(const f32x4*)(shv + c0);
  u16x4 o;
#pragma unroll
  for (int j = 0; j < 4; ++j) {
    float v = fmaf(x[j], sv[j], hv[j]);
    v = v >= 0.f ? v : alpha * v;
    o[j] = f2bf(v);
  }
  *(u16x4*)(z + (long)idx * 4) = o;
}

// w = prelu(bn(G3)) fp32, + global sum (for wn = w/w_sum)
__global__ void wbuild_k(const float* __restrict__ G, const float* __restrict__ scv,
                         const float* __restrict__ shv,
                         const float* __restrict__ alphaPtr,
                         float* __restrict__ w, float* __restrict__ wsum) {
  const int idx = blockIdx.x * 256 + threadIdx.x;  // exactly 65536 threads
  const float alpha = alphaPtr[0];
  const int c0 = (idx * 4) & 63;
  f32x4 x = *(const f32x4*)(G + (long)idx * 4);
  f32x4 sv = *(const f32x4*)(scv + c0);
  f32x4 hv = *(const f32x4*)(shv + c0);
  f32x4 o;
  float part = 0.f;
#pragma unroll
  for (int j = 0; j < 4; ++j) {
    float v = fmaf(x[j], sv[j], hv[j]);
    v = v >= 0.f ? v : alpha * v;
    o[j] = v;
    part += v;
  }
  *(f32x4*)(w + (long)idx * 4) = o;
  __shared__ float sb[256];
  sb[threadIdx.x] = part;
  __syncthreads();
  for (int st = 128; st > 0; st >>= 1) {
    if (threadIdx.x < st) sb[threadIdx.x] += sb[threadIdx.x + st];
    __syncthreads();
  }
  if (threadIdx.x == 0) atomicAdd(wsum, sb[0]);
}

__global__ void inv_k(const float* __restrict__ wsum, float* __restrict__ invp) {
  if (threadIdx.x == 0 && blockIdx.x == 0) invp[0] = 1.0f / wsum[0];
}

__global__ void cast_k(const float* __restrict__ x, unsigned short* __restrict__ z,
                       int total4) {
  const int idx = blockIdx.x * 256 + threadIdx.x;
  if (idx >= total4) return;
  f32x4 v = *(const f32x4*)(x + (long)idx * 4);
  u16x4 o;
#pragma unroll
  for (int j = 0; j < 4; ++j) o[j] = f2bf(v[j]);
  *(u16x4*)(z + (long)idx * 4) = o;
}

// W[e,o,i] fp32 (+bias[e,o] folded as K rows EI..EI+E) -> fragment-major bf16
__global__ void prepack_k(const float* __restrict__ W, const float* __restrict__ bias,
                          unsigned short* __restrict__ PB, int O, int shI, int EI,
                          long totalChunks) {
  const long t = (long)blockIdx.x * 256 + threadIdx.x;
  if (t >= totalChunks) return;
  const int lane = (int)(t & 63);
  const long frag = t >> 6;
  const int nsubs = O / 16;
  const int nsub = (int)(frag % nsubs);
  const long ktile = frag / nsubs;
  const int n = nsub * 16 + (lane & 15);
  const int k = (int)(ktile * 32 + (lane >> 4) * 8);
  u16x8 o;
  if (k < EI) {
    const int e = k >> shI;
    const int i0 = k & ((1 << shI) - 1);
    const float* src = W + ((long)e * O + n) * (1 << shI) + i0;
    f32x4 a0 = *(const f32x4*)src;
    f32x4 a1 = *(const f32x4*)(src + 4);
#pragma unroll
    for (int j = 0; j < 4; ++j) {
      o[j] = f2bf(a0[j]);
      o[4 + j] = f2bf(a1[j]);
    }
  } else {
#pragma unroll
    for (int j = 0; j < 8; ++j) {
      const int ee = k + j - EI;
      o[j] = f2bf(bias[(long)ee * O + n]);
    }
  }
  *(u16x8*)(PB + t * 8) = o;
}

__global__ void reduceN_k(const float* __restrict__ P, long partStride, int nparts,
                          float* __restrict__ out, int total4) {
  const int idx = blockIdx.x * 256 + threadIdx.x;
  if (idx >= total4) return;
  f32x4 s = {0.f, 0.f, 0.f, 0.f};
  for (int p = 0; p < nparts; ++p) s += *(const f32x4*)(P + p * partStride + (long)idx * 4);
  *(f32x4*)(out + (long)idx * 4) = s;
}

// ---------------------------------------------------------------------------
extern "C" void kernel_launch(void* const* d_in, const int* in_sizes, int n_in,
                              void* d_out, int out_size, void* d_ws, size_t ws_size,
                              hipStream_t stream) {
  const float* m0 = (const float*)d_in[0];
  const float* x0 = (const float*)d_in[1];
  const float* mW1 = (const float*)d_in[2];
  const float* mb1 = (const float*)d_in[3];
  const float* mg1 = (const float*)d_in[4];
  const float* mbe1 = (const float*)d_in[5];
  const float* ma1 = (const float*)d_in[6];
  const float* mW2 = (const float*)d_in[7];
  const float* mb2 = (const float*)d_in[8];
  const float* mg2 = (const float*)d_in[9];
  const float* mbe2 = (const float*)d_in[10];
  const float* ma2 = (const float*)d_in[11];
  const float* mW3 = (const float*)d_in[12];
  const float* mb3 = (const float*)d_in[13];
  const float* mg3 = (const float*)d_in[14];
  const float* mbe3 = (const float*)d_in[15];
  const float* ma3 = (const float*)d_in[16];
  const float* Wenc0 = (const float*)d_in[17];
  const float* benc0 = (const float*)d_in[18];
  const float* Wenc1 = (const float*)d_in[19];
  const float* benc1 = (const float*)d_in[20];
  const float* Wdec0 = (const float*)d_in[21];
  const float* bdec0 = (const float*)d_in[22];
  const float* Wdec1 = (const float*)d_in[23];
  const float* bdec1 = (const float*)d_in[24];
  const float* bng = (const float*)d_in[25];
  const float* bnb = (const float*)d_in[26];
  const float* aexp = (const float*)d_in[27];

  // Split-K width for the expert GEMMs: 8 gives 512 blocks = 2 blocks/CU
  // (round-2 counters: 256 blocks = 1 block/CU = 1 wave/SIMD, fully
  // latency-exposed, MfmaUtil 10.6%). Needs 32MB of partials; gate on ws_size.
  const int SPL = (ws_size >= (size_t)52 * 1024 * 1024) ? 8 : 4;
  const int SPLD = SPL * 2;  // dec1 (N=64) splits: partials are 4x smaller

  char* base = (char*)d_ws;
  size_t off = 0;
  auto alloc = [&](size_t bytes) {
    void* p = base + off;
    off = (off + bytes + 255) & ~(size_t)255;
    return p;
  };
  unsigned short* PB = (unsigned short*)alloc(16448L * 256 * 2);  // 8.4 MB, reused per layer
  float* Pb = (float*)alloc((size_t)SPL * BATCH * 256 * 4);       // split-K partials
  float* P0 = Pb;                      // also MNet activations [4096,256]
  float* P1 = Pb + (long)BATCH * 256;  // MNet hidden [4096,128]
  unsigned short* zA = (unsigned short*)alloc(BATCH * 256 * 2);
  unsigned short* zB = (unsigned short*)alloc(BATCH * 256 * 2);
  unsigned short* zx0 = (unsigned short*)alloc(BATCH * 64 * 2);
  float* wbuf = (float*)alloc(BATCH * 64 * 4);
  float* scv = (float*)alloc(256 * 4);
  float* shv = (float*)alloc(256 * 4);
  float* wsum = (float*)alloc(256);
  float* invp = (float*)alloc(256);

  const dim3 blk(256);
  const long PS = BATCH * 256;  // partial stride (elements)

  // ---- MNet L1: G1 = m0 @ mW1^T + mb1  -> P0 [4096,256]
  prepack_k<<<16, blk, 0, stream>>>(mW1, nullptr, PB, 256, 7, 128, 4096);
  gemm_k<128, 2, 2, AM_PLAIN><<<dim3(32, 2, 1), blk, 0, stream>>>(
      m0, nullptr, nullptr, nullptr, nullptr, nullptr, nullptr, 0, 0, PB, 128, 16,
      P0, 0, mb1, 256, 2, 1);
  stats_k<<<64, blk, 0, stream>>>(P0, 0, 1, 256, mg1, mbe1, scv, shv);

  // ---- MNet L2: G2 = prelu(bn(G1)) @ mW2^T + mb2 -> P1 [4096,128]
  prepack_k<<<16, blk, 0, stream>>>(mW2, nullptr, PB, 128, 8, 256, 4096);
  gemm_k<128, 2, 2, AM_BN><<<dim3(32, 1, 1), blk, 0, stream>>>(
      P0, scv, shv, ma1, nullptr, nullptr, nullptr, 0, 0, PB, 256, 8, P1, 0, mb2,
      128, 4, 1);
  stats_k<<<32, blk, 0, stream>>>(P1, 0, 1, 128, mg2, mbe2, scv, shv);

  // ---- MNet L3: G3 = prelu(bn(G2)) @ mW3^T + mb3 -> P0 [4096,64]
  prepack_k<<<4, blk, 0, stream>>>(mW3, nullptr, PB, 64, 7, 128, 1024);
  gemm_k<64, 4, 1, AM_BN><<<dim3(32, 1, 1), blk, 0, stream>>>(
      P1, scv, shv, ma2, nullptr, nullptr, nullptr, 0, 0, PB, 128, 4, P0, 0, mb3,
      64, 2, 1);
  stats_k<<<16, blk, 0, stream>>>(P0, 0, 1, 64, mg3, mbe3, scv, shv);

  // ---- w = prelu(bn(G3)); w_sum; inv; x0 -> bf16
  hipMemsetAsync(wsum, 0, 4, stream);
  wbuild_k<<<256, blk, 0, stream>>>(P0, scv, shv, ma3, wbuf, wsum);
  inv_k<<<1, 64, 0, stream>>>(wsum, invp);
  cast_k<<<256, blk, 0, stream>>>(x0, zx0, 65536);

  // ---- enc0: K=64*64+64=4160
  prepack_k<<<520, blk, 0, stream>>>(Wenc0, benc0, PB, 256, 6, 4096, 133120);
  gemm_k<128, 2, 2, AM_EXPERT><<<dim3(32, 2, SPL), blk, 0, stream>>>(
      nullptr, nullptr, nullptr, nullptr, zx0, wbuf, invp, 6, 4096, PB, 4160, 16,
      Pb, PS, nullptr, 256, 65, SPL);
  stats_k<<<64, blk, 0, stream>>>(Pb, PS, SPL, 256, bng, bnb, scv, shv);
  zbuild_k<<<1024, blk, 0, stream>>>(Pb, PS, SPL, scv, shv, aexp, zA, 256, 262144);

  // ---- enc1: K=64*256+64=16448
  prepack_k<<<2056, blk, 0, stream>>>(Wenc1, benc1, PB, 256, 8, 16384, 526336);
  gemm_k<128, 2, 2, AM_EXPERT><<<dim3(32, 2, SPL), blk, 0, stream>>>(
      nullptr, nullptr, nullptr, nullptr, zA, wbuf, invp, 8, 16384, PB, 16448, 16,
      Pb, PS, nullptr, 256, 257, SPL);
  stats_k<<<64, blk, 0, stream>>>(Pb, PS, SPL, 256, bng, bnb, scv, shv);
  zbuild_k<<<1024, blk, 0, stream>>>(Pb, PS, SPL, scv, shv, aexp, zB, 256, 262144);

  // ---- dec0
  prepack_k<<<2056, blk, 0, stream>>>(Wdec0, bdec0, PB, 256, 8, 16384, 526336);
  gemm_k<128, 2, 2, AM_EXPERT><<<dim3(32, 2, SPL), blk, 0, stream>>>(
      nullptr, nullptr, nullptr, nullptr, zB, wbuf, invp, 8, 16384, PB, 16448, 16,
      Pb, PS, nullptr, 256, 257, SPL);
  stats_k<<<64, blk, 0, stream>>>(Pb, PS, SPL, 256, bng, bnb, scv, shv);
  zbuild_k<<<1024, blk, 0, stream>>>(Pb, PS, SPL, scv, shv, aexp, zA, 256, 262144);

  // ---- dec1: N=64 -> SPLD partials of [4096,64]
  prepack_k<<<514, blk, 0, stream>>>(Wdec1, bdec1, PB, 64, 8, 16384, 131584);
  gemm_k<64, 4, 1, AM_EXPERT><<<dim3(32, 1, SPLD), blk, 0, stream>>>(
      nullptr, nullptr, nullptr, nullptr, zA, wbuf, invp, 8, 16384, PB, 16448, 4,
      Pb, (long)BATCH * 64, nullptr, 64, 257, SPLD);
  reduceN_k<<<256, blk, 0, stream>>>(Pb, (long)BATCH * 64, SPLD, (float*)d_out, 65536);

  (void)in_sizes; (void)n_in; (void)out_size; (void)ws_size;
}

// Round 4
// 503.810 us; speedup vs baseline: 1.4460x; 1.4460x over previous
//
#include <hip/hip_runtime.h>
#include <stdint.h>

#define BATCH 4096
#define NEXP 64

typedef __bf16 bf16x8 __attribute__((ext_vector_type(8)));
typedef float f32x4 __attribute__((ext_vector_type(4)));
typedef float f32x8 __attribute__((ext_vector_type(8)));
typedef unsigned int u32x4 __attribute__((ext_vector_type(4)));
typedef unsigned short u16x4 __attribute__((ext_vector_type(4)));
typedef unsigned short u16x8 __attribute__((ext_vector_type(8)));

__device__ __forceinline__ unsigned short f2bf(float f) {
  unsigned u = __builtin_bit_cast(unsigned, f);
  u += 0x7fffu + ((u >> 16) & 1u);
  return (unsigned short)(u >> 16);
}
__device__ __forceinline__ float bf2f(unsigned short h) {
  unsigned u = ((unsigned)h) << 16;
  return __builtin_bit_cast(float, u);
}

// async global->LDS, 16B per lane. LDS dest = wave-uniform base + lane*16.
__device__ __forceinline__ void async_copy16(const void* g, void* l) {
  __builtin_amdgcn_global_load_lds(
      (const __attribute__((address_space(1))) void*)(uintptr_t)g,
      (__attribute__((address_space(3))) void*)(uintptr_t)l, 16, 0, 0);
}

enum { AM_PLAIN = 0, AM_BN = 1, AM_EXPERT = 2 };

// ---------------------------------------------------------------------------
// Generic MFMA GEMM: C_slice[b,n] = sum_k A(b,k) * PB(k,n)  (+ bias[n])
//   B (PB) fragment-major packed bf16 (MFMA B-operand layout), staged via
//   global_load_lds. A built on the fly into LDS (conflict-free id*16B map).
//   Round-4: BM=64 -> grid 1024 blocks = 4 blocks/CU = 16 waves/CU (round-3
//   counters: 2 blocks/CU left MfmaUtil at 13%, pure latency exposure).
//   AM_EXPERT uses prescaled bf16 wn (wnb): product path = 2 L1 loads + 8 FMA
//   + packed cvt; folded-bias K-rows are a raw 16B copy.
// ---------------------------------------------------------------------------
template <int BM_, int BN_, int WR, int WC, int AMODE>
__global__ __launch_bounds__(256, 4) void gemm_k(
    const float* __restrict__ Af32, const float* __restrict__ scv,
    const float* __restrict__ shv, const float* __restrict__ alphaPtr,
    const unsigned short* __restrict__ zbf, const unsigned short* __restrict__ wnb,
    int shI, int EI,
    const unsigned short* __restrict__ PB, int K, int nsubsTot,
    float* __restrict__ Cbase, long partStride,
    const float* __restrict__ biasv, int N, int ktilesTot, int splits) {
  constexpr int BK = 64;
  constexpr int MS = BM_ / 16;  // A subtiles
  constexpr int NS = BN_ / 16;  // B subtiles per block
  constexpr int WTM = BM_ / WR, WTN = BN_ / WC;
  constexpr int TM = WTM / 16, TN = WTN / 16;
  constexpr int PCH = MS / 2;  // A chunks per thread (2*MS*64 chunks / 256 thr)

  __shared__ __align__(16) unsigned short As[2 * MS * 512];
  __shared__ __align__(16) unsigned short Bs[2 * NS * 512];

  const int tid = threadIdx.x;
  const int lane = tid & 63;
  const int wid = tid >> 6;
  const int wrow = wid / WC, wcol = wid % WC;

  const int m0 = blockIdx.x * BM_;
  const int ntile = blockIdx.y;
  const int n0 = ntile * BN_;
  const int slice = blockIdx.z;
  const int kt0 = (int)((long)slice * ktilesTot / splits);
  const int kt1 = (int)((long)(slice + 1) * ktilesTot / splits);

  float* __restrict__ Cp = Cbase + (long)slice * partStride;

  float alpha = 0.f;
  if constexpr (AMODE == AM_BN) alpha = alphaPtr[0];

  f32x4 acc[TM][TN] = {};

  for (int kt = kt0; kt < kt1; ++kt) {
    const int k0 = kt * BK;

    // ---- stage B: 2*NS fragments of 1KB, one wave-instruction each
    for (int f = wid; f < 2 * NS; f += 4) {
      const int fkt = f / NS, fns = f % NS;
      const long fragIdx = (long)(k0 / 32 + fkt) * nsubsTot + (ntile * NS + fns);
      async_copy16(PB + fragIdx * 512 + lane * 8, &Bs[f * 512 + lane * 8]);
    }

    // ---- stage A: 2*MS*64 16B chunks; chunk id = p*256+tid (conflict-free)
#pragma unroll
    for (int p = 0; p < PCH; ++p) {
      const int id = p * 256 + tid;
      const int fA = id >> 6;  // fragment = ksh*MS + msub
      const int q = id & 63;   // chunk within fragment
      const int ksh = fA / MS, msub = fA % MS;
      const int kq = q >> 4, mrow = q & 15;
      const int m = msub * 16 + mrow;
      const int kg = k0 + ksh * 32 + kq * 8;
      const long mg = m0 + m;
      if constexpr (AMODE == AM_EXPERT) {
        if (kg >= EI) {  // folded-bias region: raw copy of prescaled wn bf16
          u16x8 ww = *(const u16x8*)(wnb + mg * NEXP + (kg - EI));
          *(u16x8*)&As[id * 8] = ww;
          continue;
        }
      }
      f32x8 vf;
      if constexpr (AMODE == AM_PLAIN) {
        const f32x4* src = (const f32x4*)(Af32 + mg * K + kg);
        f32x4 a0 = src[0], a1 = src[1];
#pragma unroll
        for (int j = 0; j < 4; ++j) { vf[j] = a0[j]; vf[4 + j] = a1[j]; }
      } else if constexpr (AMODE == AM_BN) {
        const f32x4* src = (const f32x4*)(Af32 + mg * K + kg);
        f32x4 a0 = src[0], a1 = src[1];
        f32x4 s0 = *(const f32x4*)(scv + kg), s1 = *(const f32x4*)(scv + kg + 4);
        f32x4 h0 = *(const f32x4*)(shv + kg), h1 = *(const f32x4*)(shv + kg + 4);
#pragma unroll
        for (int j = 0; j < 4; ++j) {
          float v = fmaf(a0[j], s0[j], h0[j]);
          vf[j] = v >= 0.f ? v : alpha * v;
          float v2 = fmaf(a1[j], s1[j], h1[j]);
          vf[4 + j] = v2 >= 0.f ? v2 : alpha * v2;
        }
      } else {  // AM_EXPERT product region: A = wn[b,e] * z[b,i]
        const int e = kg >> shI;
        const int i0 = kg & ((1 << shI) - 1);
        const float wv = bf2f(wnb[mg * NEXP + e]);
        u16x8 zz = *(const u16x8*)(zbf + ((long)mg << shI) + i0);
#pragma unroll
        for (int j = 0; j < 8; ++j) vf[j] = wv * bf2f(zz[j]);
      }
      bf16x8 ob = __builtin_convertvector(vf, bf16x8);
      *(u16x8*)&As[id * 8] = __builtin_bit_cast(u16x8, ob);
    }
    __syncthreads();

    // ---- MFMA
#pragma unroll
    for (int ks = 0; ks < 2; ++ks) {
      bf16x8 af[TM], bfr[TN];
#pragma unroll
      for (int i = 0; i < TM; ++i) {
        const int msub = wrow * TM + i;
        af[i] = __builtin_bit_cast(
            bf16x8, *(const u32x4*)&As[(ks * MS + msub) * 512 + lane * 8]);
      }
#pragma unroll
      for (int j = 0; j < TN; ++j) {
        const int nsub = wcol * TN + j;
        bfr[j] = __builtin_bit_cast(
            bf16x8, *(const u32x4*)&Bs[(ks * NS + nsub) * 512 + lane * 8]);
      }
#pragma unroll
      for (int i = 0; i < TM; ++i)
#pragma unroll
        for (int j = 0; j < TN; ++j)
          acc[i][j] = __builtin_amdgcn_mfma_f32_16x16x32_bf16(af[i], bfr[j],
                                                              acc[i][j], 0, 0, 0);
    }
    __syncthreads();
  }

  // ---- epilogue: C/D layout col=lane&15, row=(lane>>4)*4+reg
  const int q = lane >> 4, nn = lane & 15;
#pragma unroll
  for (int i = 0; i < TM; ++i) {
    const int rowb = m0 + wrow * WTM + i * 16 + q * 4;
#pragma unroll
    for (int j = 0; j < TN; ++j) {
      const int col = n0 + wcol * WTN + j * 16 + nn;
      const float bv = biasv ? biasv[col] : 0.f;
#pragma unroll
      for (int r = 0; r < 4; ++r)
        Cp[(long)(rowb + r) * N + col] = acc[i][j][r] + bv;
    }
  }
}

// H[idx] = sum over nparts partials, written in place over partial 0.
__global__ void hbuild_k(float* __restrict__ P, long partStride, int nparts,
                         int total4) {
  const int idx = blockIdx.x * 256 + threadIdx.x;
  if (idx >= total4) return;
  f32x4 s = *(const f32x4*)(P + (long)idx * 4);
  for (int p = 1; p < nparts; ++p)
    s += *(const f32x4*)(P + p * partStride + (long)idx * 4);
  *(f32x4*)(P + (long)idx * 4) = s;
}

// ---------------------------------------------------------------------------
// BN stats: 4 columns per block, float4 row reads.
// Emits sc=g*rsqrt(var+eps), sh=b-mu*sc  (biased var, eps=1e-5)
// ---------------------------------------------------------------------------
__global__ void stats_k(const float* __restrict__ H, int C,
                        const float* __restrict__ g, const float* __restrict__ b,
                        float* __restrict__ scv, float* __restrict__ shv) {
  const int c0 = blockIdx.x * 4;
  f32x4 s = {0.f, 0.f, 0.f, 0.f}, s2 = {0.f, 0.f, 0.f, 0.f};
  for (int r = threadIdx.x; r < BATCH; r += 256) {
    f32x4 x = *(const f32x4*)(H + (long)r * C + c0);
    s += x;
    s2 += x * x;
  }
  __shared__ f32x4 sb[256], qb[256];
  sb[threadIdx.x] = s;
  qb[threadIdx.x] = s2;
  __syncthreads();
  for (int st = 128; st > 0; st >>= 1) {
    if (threadIdx.x < st) {
      sb[threadIdx.x] += sb[threadIdx.x + st];
      qb[threadIdx.x] += qb[threadIdx.x + st];
    }
    __syncthreads();
  }
  if (threadIdx.x < 4) {
    const int c = c0 + threadIdx.x;
    float mu = sb[0][threadIdx.x] * (1.f / BATCH);
    float var = qb[0][threadIdx.x] * (1.f / BATCH) - mu * mu;
    float isig = 1.f / sqrtf(var + 1e-5f);
    float sc_ = g[c] * isig;
    scv[c] = sc_;
    shv[c] = b[c] - mu * sc_;
  }
}

// z = bf16(prelu(sc*H+sh))
__global__ void zbuild_k(const float* __restrict__ H,
                         const float* __restrict__ scv,
                         const float* __restrict__ shv,
                         const float* __restrict__ alphaPtr,
                         unsigned short* __restrict__ z, int C, int total4) {
  const int idx = blockIdx.x * 256 + threadIdx.x;
  if (idx >= total4) return;
  const float alpha = alphaPtr[0];
  const int c0 = (idx * 4) & (C - 1);
  f32x4 x = *(const f32x4*)(H + (long)idx * 4);
  f32x4 sv = *(const f32x4*)(scv + c0);
  f32x4 hv = *(const f32x4*)(shv + c0);
  u16x4 o;
#pragma unroll
  for (int j = 0; j < 4; ++j) {
    float v = fmaf(x[j], sv[j], hv[j]);
    v = v >= 0.f ? v : alpha * v;
    o[j] = f2bf(v);
  }
  *(u16x4*)(z + (long)idx * 4) = o;
}

// w = prelu(bn(G3)) fp32, + global sum (for wn = w/w_sum)
__global__ void wbuild_k(const float* __restrict__ G, const float* __restrict__ scv,
                         const float* __restrict__ shv,
                         const float* __restrict__ alphaPtr,
                         float* __restrict__ w, float* __restrict__ wsum) {
  const int idx = blockIdx.x * 256 + threadIdx.x;  // exactly 65536 threads
  const float alpha = alphaPtr[0];
  const int c0 = (idx * 4) & 63;
  f32x4 x = *(const f32x4*)(G + (long)idx * 4);
  f32x4 sv = *(const f32x4*)(scv + c0);
  f32x4 hv = *(const f32x4*)(shv + c0);
  f32x4 o;
  float part = 0.f;
#pragma unroll
  for (int j = 0; j < 4; ++j) {
    float v = fmaf(x[j], sv[j], hv[j]);
    v = v >= 0.f ? v : alpha * v;
    o[j] = v;
    part += v;
  }
  *(f32x4*)(w + (long)idx * 4) = o;
  __shared__ float sb[256];
  sb[threadIdx.x] = part;
  __syncthreads();
  for (int st = 128; st > 0; st >>= 1) {
    if (threadIdx.x < st) sb[threadIdx.x] += sb[threadIdx.x + st];
    __syncthreads();
  }
  if (threadIdx.x == 0) atomicAdd(wsum, sb[0]);
}

__global__ void inv_k(const float* __restrict__ wsum, float* __restrict__ invp) {
  if (threadIdx.x == 0 && blockIdx.x == 0) invp[0] = 1.0f / wsum[0];
}

// wnb = bf16(w * inv)  [4096*64], the prescaled expert weights
__global__ void wnbuild_k(const float* __restrict__ w, const float* __restrict__ invp,
                          unsigned short* __restrict__ wnb) {
  const int idx = blockIdx.x * 256 + threadIdx.x;  // 65536 threads
  const float inv = invp[0];
  f32x4 v = *(const f32x4*)(w + (long)idx * 4);
  u16x4 o;
#pragma unroll
  for (int j = 0; j < 4; ++j) o[j] = f2bf(v[j] * inv);
  *(u16x4*)(wnb + (long)idx * 4) = o;
}

__global__ void cast_k(const float* __restrict__ x, unsigned short* __restrict__ z,
                       int total4) {
  const int idx = blockIdx.x * 256 + threadIdx.x;
  if (idx >= total4) return;
  f32x4 v = *(const f32x4*)(x + (long)idx * 4);
  u16x4 o;
#pragma unroll
  for (int j = 0; j < 4; ++j) o[j] = f2bf(v[j]);
  *(u16x4*)(z + (long)idx * 4) = o;
}

// W[e,o,i] fp32 (+bias[e,o] folded as K rows EI..EI+E) -> fragment-major bf16
__global__ void prepack_k(const float* __restrict__ W, const float* __restrict__ bias,
                          unsigned short* __restrict__ PB, int O, int shI, int EI,
                          long totalChunks) {
  const long t = (long)blockIdx.x * 256 + threadIdx.x;
  if (t >= totalChunks) return;
  const int lane = (int)(t & 63);
  const long frag = t >> 6;
  const int nsubs = O / 16;
  const int nsub = (int)(frag % nsubs);
  const long ktile = frag / nsubs;
  const int n = nsub * 16 + (lane & 15);
  const int k = (int)(ktile * 32 + (lane >> 4) * 8);
  u16x8 o;
  if (k < EI) {
    const int e = k >> shI;
    const int i0 = k & ((1 << shI) - 1);
    const float* src = W + ((long)e * O + n) * (1 << shI) + i0;
    f32x4 a0 = *(const f32x4*)src;
    f32x4 a1 = *(const f32x4*)(src + 4);
#pragma unroll
    for (int j = 0; j < 4; ++j) {
      o[j] = f2bf(a0[j]);
      o[4 + j] = f2bf(a1[j]);
    }
  } else {
#pragma unroll
    for (int j = 0; j < 8; ++j) {
      const int ee = k + j - EI;
      o[j] = f2bf(bias[(long)ee * O + n]);
    }
  }
  *(u16x8*)(PB + t * 8) = o;
}

__global__ void reduceN_k(const float* __restrict__ P, long partStride, int nparts,
                          float* __restrict__ out, int total4) {
  const int idx = blockIdx.x * 256 + threadIdx.x;
  if (idx >= total4) return;
  f32x4 s = {0.f, 0.f, 0.f, 0.f};
  for (int p = 0; p < nparts; ++p) s += *(const f32x4*)(P + p * partStride + (long)idx * 4);
  *(f32x4*)(out + (long)idx * 4) = s;
}

// ---------------------------------------------------------------------------
extern "C" void kernel_launch(void* const* d_in, const int* in_sizes, int n_in,
                              void* d_out, int out_size, void* d_ws, size_t ws_size,
                              hipStream_t stream) {
  const float* m0 = (const float*)d_in[0];
  const float* x0 = (const float*)d_in[1];
  const float* mW1 = (const float*)d_in[2];
  const float* mb1 = (const float*)d_in[3];
  const float* mg1 = (const float*)d_in[4];
  const float* mbe1 = (const float*)d_in[5];
  const float* ma1 = (const float*)d_in[6];
  const float* mW2 = (const float*)d_in[7];
  const float* mb2 = (const float*)d_in[8];
  const float* mg2 = (const float*)d_in[9];
  const float* mbe2 = (const float*)d_in[10];
  const float* ma2 = (const float*)d_in[11];
  const float* mW3 = (const float*)d_in[12];
  const float* mb3 = (const float*)d_in[13];
  const float* mg3 = (const float*)d_in[14];
  const float* mbe3 = (const float*)d_in[15];
  const float* ma3 = (const float*)d_in[16];
  const float* Wenc0 = (const float*)d_in[17];
  const float* benc0 = (const float*)d_in[18];
  const float* Wenc1 = (const float*)d_in[19];
  const float* benc1 = (const float*)d_in[20];
  const float* Wdec0 = (const float*)d_in[21];
  const float* bdec0 = (const float*)d_in[22];
  const float* Wdec1 = (const float*)d_in[23];
  const float* bdec1 = (const float*)d_in[24];
  const float* bng = (const float*)d_in[25];
  const float* bnb = (const float*)d_in[26];
  const float* aexp = (const float*)d_in[27];

  // ws >= 52MB proven in round 3 (SPL=8 ran). Keep gate + fallback anyway.
  const bool big = ws_size >= (size_t)52 * 1024 * 1024;
  const int SPL = big ? 8 : 4;    // expert-layer split-K (partials: SPL*4MB)
  const int SPLD = big ? 16 : 8;  // dec1 split-K (partials: SPLD*1MB)

  char* base = (char*)d_ws;
  size_t off = 0;
  auto alloc = [&](size_t bytes) {
    void* p = base + off;
    off = (off + bytes + 255) & ~(size_t)255;
    return p;
  };
  unsigned short* PB = (unsigned short*)alloc(16448L * 256 * 2);  // 8.4 MB
  float* Pb = (float*)alloc((size_t)SPL * BATCH * 256 * 4);       // split-K partials
  float* P0 = Pb;                      // MNet H1 [4096,256] / H3 [4096,64]
  float* P1 = Pb + (long)BATCH * 256;  // MNet H2 [4096,128]
  unsigned short* zA = (unsigned short*)alloc(BATCH * 256 * 2);
  unsigned short* zB = (unsigned short*)alloc(BATCH * 256 * 2);
  unsigned short* zx0 = (unsigned short*)alloc(BATCH * 64 * 2);
  float* wbuf = (float*)alloc(BATCH * 64 * 4);
  unsigned short* wnb = (unsigned short*)alloc(BATCH * 64 * 2);
  float* scv = (float*)alloc(256 * 4);
  float* shv = (float*)alloc(256 * 4);
  float* wsum = (float*)alloc(256);
  float* invp = (float*)alloc(256);

  const dim3 blk(256);
  const long PS = BATCH * 256;  // partial stride (elements)

  // ---- MNet L1: H1 = m0 @ mW1^T + mb1 -> P0 [4096,256]
  prepack_k<<<16, blk, 0, stream>>>(mW1, nullptr, PB, 256, 7, 128, 4096);
  gemm_k<64, 128, 2, 2, AM_PLAIN><<<dim3(64, 2, 1), blk, 0, stream>>>(
      m0, nullptr, nullptr, nullptr, nullptr, nullptr, 0, 0, PB, 128, 16,
      P0, 0, mb1, 256, 2, 1);
  stats_k<<<64, blk, 0, stream>>>(P0, 256, mg1, mbe1, scv, shv);

  // ---- MNet L2: H2 = prelu(bn(H1)) @ mW2^T + mb2 -> P1 [4096,128]
  prepack_k<<<16, blk, 0, stream>>>(mW2, nullptr, PB, 128, 8, 256, 4096);
  gemm_k<64, 128, 2, 2, AM_BN><<<dim3(64, 1, 1), blk, 0, stream>>>(
      P0, scv, shv, ma1, nullptr, nullptr, 0, 0, PB, 256, 8, P1, 0, mb2,
      128, 4, 1);
  stats_k<<<32, blk, 0, stream>>>(P1, 128, mg2, mbe2, scv, shv);

  // ---- MNet L3: H3 = prelu(bn(H2)) @ mW3^T + mb3 -> P0 [4096,64]
  prepack_k<<<4, blk, 0, stream>>>(mW3, nullptr, PB, 64, 7, 128, 1024);
  gemm_k<64, 64, 2, 2, AM_BN><<<dim3(64, 1, 1), blk, 0, stream>>>(
      P1, scv, shv, ma2, nullptr, nullptr, 0, 0, PB, 128, 4, P0, 0, mb3,
      64, 2, 1);
  stats_k<<<16, blk, 0, stream>>>(P0, 64, mg3, mbe3, scv, shv);

  // ---- w = prelu(bn(H3)); w_sum; wnb = bf16(w/w_sum); x0 -> bf16
  hipMemsetAsync(wsum, 0, 4, stream);
  wbuild_k<<<256, blk, 0, stream>>>(P0, scv, shv, ma3, wbuf, wsum);
  inv_k<<<1, 64, 0, stream>>>(wsum, invp);
  wnbuild_k<<<256, blk, 0, stream>>>(wbuf, invp, wnb);
  cast_k<<<256, blk, 0, stream>>>(x0, zx0, 65536);

  // ---- enc0: K=64*64+64=4160
  prepack_k<<<520, blk, 0, stream>>>(Wenc0, benc0, PB, 256, 6, 4096, 133120);
  gemm_k<64, 128, 2, 2, AM_EXPERT><<<dim3(64, 2, SPL), blk, 0, stream>>>(
      nullptr, nullptr, nullptr, nullptr, zx0, wnb, 6, 4096, PB, 4160, 16,
      Pb, PS, nullptr, 256, 65, SPL);
  hbuild_k<<<1024, blk, 0, stream>>>(Pb, PS, SPL, 262144);
  stats_k<<<64, blk, 0, stream>>>(Pb, 256, bng, bnb, scv, shv);
  zbuild_k<<<1024, blk, 0, stream>>>(Pb, scv, shv, aexp, zA, 256, 262144);

  // ---- enc1: K=64*256+64=16448
  prepack_k<<<2056, blk, 0, stream>>>(Wenc1, benc1, PB, 256, 8, 16384, 526336);
  gemm_k<64, 128, 2, 2, AM_EXPERT><<<dim3(64, 2, SPL), blk, 0, stream>>>(
      nullptr, nullptr, nullptr, nullptr, zA, wnb, 8, 16384, PB, 16448, 16,
      Pb, PS, nullptr, 256, 257, SPL);
  hbuild_k<<<1024, blk, 0, stream>>>(Pb, PS, SPL, 262144);
  stats_k<<<64, blk, 0, stream>>>(Pb, 256, bng, bnb, scv, shv);
  zbuild_k<<<1024, blk, 0, stream>>>(Pb, scv, shv, aexp, zB, 256, 262144);

  // ---- dec0
  prepack_k<<<2056, blk, 0, stream>>>(Wdec0, bdec0, PB, 256, 8, 16384, 526336);
  gemm_k<64, 128, 2, 2, AM_EXPERT><<<dim3(64, 2, SPL), blk, 0, stream>>>(
      nullptr, nullptr, nullptr, nullptr, zB, wnb, 8, 16384, PB, 16448, 16,
      Pb, PS, nullptr, 256, 257, SPL);
  hbuild_k<<<1024, blk, 0, stream>>>(Pb, PS, SPL, 262144);
  stats_k<<<64, blk, 0, stream>>>(Pb, 256, bng, bnb, scv, shv);
  zbuild_k<<<1024, blk, 0, stream>>>(Pb, scv, shv, aexp, zA, 256, 262144);

  // ---- dec1: N=64 -> SPLD partials of [4096,64]
  prepack_k<<<514, blk, 0, stream>>>(Wdec1, bdec1, PB, 64, 8, 16384, 131584);
  gemm_k<64, 64, 2, 2, AM_EXPERT><<<dim3(64, 1, SPLD), blk, 0, stream>>>(
      nullptr, nullptr, nullptr, nullptr, zA, wnb, 8, 16384, PB, 16448, 4,
      Pb, (long)BATCH * 64, nullptr, 64, 257, SPLD);
  reduceN_k<<<256, blk, 0, stream>>>(Pb, (long)BATCH * 64, SPLD, (float*)d_out, 65536);

  (void)in_sizes; (void)n_in; (void)out_size;
}

// Round 5
// 418.414 us; speedup vs baseline: 1.7411x; 1.2041x over previous
//
#include <hip/hip_runtime.h>
#include <stdint.h>

#define BATCH 4096
#define NEXP 64

typedef __bf16 bf16x8 __attribute__((ext_vector_type(8)));
typedef float f32x4 __attribute__((ext_vector_type(4)));
typedef float f32x8 __attribute__((ext_vector_type(8)));
typedef unsigned int u32x4 __attribute__((ext_vector_type(4)));
typedef unsigned short u16x4 __attribute__((ext_vector_type(4)));
typedef unsigned short u16x8 __attribute__((ext_vector_type(8)));

__device__ __forceinline__ unsigned short f2bf(float f) {
  unsigned u = __builtin_bit_cast(unsigned, f);
  u += 0x7fffu + ((u >> 16) & 1u);
  return (unsigned short)(u >> 16);
}
__device__ __forceinline__ float bf2f(unsigned short h) {
  unsigned u = ((unsigned)h) << 16;
  return __builtin_bit_cast(float, u);
}

// async global->LDS, 16B per lane. LDS dest = wave-uniform base + lane*16.
__device__ __forceinline__ void async_copy16(const void* g, void* l) {
  __builtin_amdgcn_global_load_lds(
      (const __attribute__((address_space(1))) void*)(uintptr_t)g,
      (__attribute__((address_space(3))) void*)(uintptr_t)l, 16, 0, 0);
}

enum { AM_PLAIN = 0, AM_BN = 1, AM_EXPERT = 2 };

// ---------------------------------------------------------------------------
// MNet GEMM (round-4 structure, kept as-is; only AM_PLAIN/AM_BN instantiated).
// ---------------------------------------------------------------------------
template <int BM_, int BN_, int WR, int WC, int AMODE>
__global__ __launch_bounds__(256, 4) void gemm_k(
    const float* __restrict__ Af32, const float* __restrict__ scv,
    const float* __restrict__ shv, const float* __restrict__ alphaPtr,
    const unsigned short* __restrict__ zbf, const unsigned short* __restrict__ wnb,
    int shI, int EI,
    const unsigned short* __restrict__ PB, int K, int nsubsTot,
    float* __restrict__ Cbase, long partStride,
    const float* __restrict__ biasv, int N, int ktilesTot, int splits) {
  constexpr int BK = 64;
  constexpr int MS = BM_ / 16;
  constexpr int NS = BN_ / 16;
  constexpr int WTM = BM_ / WR, WTN = BN_ / WC;
  constexpr int TM = WTM / 16, TN = WTN / 16;
  constexpr int PCH = MS / 2;

  __shared__ __align__(16) unsigned short As[2 * MS * 512];
  __shared__ __align__(16) unsigned short Bs[2 * NS * 512];

  const int tid = threadIdx.x;
  const int lane = tid & 63;
  const int wid = tid >> 6;
  const int wrow = wid / WC, wcol = wid % WC;

  const int m0 = blockIdx.x * BM_;
  const int ntile = blockIdx.y;
  const int n0 = ntile * BN_;
  const int slice = blockIdx.z;
  const int kt0 = (int)((long)slice * ktilesTot / splits);
  const int kt1 = (int)((long)(slice + 1) * ktilesTot / splits);

  float* __restrict__ Cp = Cbase + (long)slice * partStride;

  float alpha = 0.f;
  if constexpr (AMODE == AM_BN) alpha = alphaPtr[0];

  f32x4 acc[TM][TN] = {};

  for (int kt = kt0; kt < kt1; ++kt) {
    const int k0 = kt * BK;

    for (int f = wid; f < 2 * NS; f += 4) {
      const int fkt = f / NS, fns = f % NS;
      const long fragIdx = (long)(k0 / 32 + fkt) * nsubsTot + (ntile * NS + fns);
      async_copy16(PB + fragIdx * 512 + lane * 8, &Bs[f * 512 + lane * 8]);
    }

#pragma unroll
    for (int p = 0; p < PCH; ++p) {
      const int id = p * 256 + tid;
      const int fA = id >> 6;
      const int q = id & 63;
      const int ksh = fA / MS, msub = fA % MS;
      const int kq = q >> 4, mrow = q & 15;
      const int m = msub * 16 + mrow;
      const int kg = k0 + ksh * 32 + kq * 8;
      const long mg = m0 + m;
      f32x8 vf;
      if constexpr (AMODE == AM_PLAIN) {
        const f32x4* src = (const f32x4*)(Af32 + mg * K + kg);
        f32x4 a0 = src[0], a1 = src[1];
#pragma unroll
        for (int j = 0; j < 4; ++j) { vf[j] = a0[j]; vf[4 + j] = a1[j]; }
      } else {
        const f32x4* src = (const f32x4*)(Af32 + mg * K + kg);
        f32x4 a0 = src[0], a1 = src[1];
        f32x4 s0 = *(const f32x4*)(scv + kg), s1 = *(const f32x4*)(scv + kg + 4);
        f32x4 h0 = *(const f32x4*)(shv + kg), h1 = *(const f32x4*)(shv + kg + 4);
#pragma unroll
        for (int j = 0; j < 4; ++j) {
          float v = fmaf(a0[j], s0[j], h0[j]);
          vf[j] = v >= 0.f ? v : alpha * v;
          float v2 = fmaf(a1[j], s1[j], h1[j]);
          vf[4 + j] = v2 >= 0.f ? v2 : alpha * v2;
        }
      }
      bf16x8 ob = __builtin_convertvector(vf, bf16x8);
      *(u16x8*)&As[id * 8] = __builtin_bit_cast(u16x8, ob);
    }
    __syncthreads();

#pragma unroll
    for (int ks = 0; ks < 2; ++ks) {
      bf16x8 af[TM], bfr[TN];
#pragma unroll
      for (int i = 0; i < TM; ++i) {
        const int msub = wrow * TM + i;
        af[i] = __builtin_bit_cast(
            bf16x8, *(const u32x4*)&As[(ks * MS + msub) * 512 + lane * 8]);
      }
#pragma unroll
      for (int j = 0; j < TN; ++j) {
        const int nsub = wcol * TN + j;
        bfr[j] = __builtin_bit_cast(
            bf16x8, *(const u32x4*)&Bs[(ks * NS + nsub) * 512 + lane * 8]);
      }
#pragma unroll
      for (int i = 0; i < TM; ++i)
#pragma unroll
        for (int j = 0; j < TN; ++j)
          acc[i][j] = __builtin_amdgcn_mfma_f32_16x16x32_bf16(af[i], bfr[j],
                                                              acc[i][j], 0, 0, 0);
    }
    __syncthreads();
  }

  const int q = lane >> 4, nn = lane & 15;
#pragma unroll
  for (int i = 0; i < TM; ++i) {
    const int rowb = m0 + wrow * WTM + i * 16 + q * 4;
#pragma unroll
    for (int j = 0; j < TN; ++j) {
      const int col = n0 + wcol * WTN + j * 16 + nn;
      const float bv = biasv ? biasv[col] : 0.f;
#pragma unroll
      for (int r = 0; r < 4; ++r)
        Cp[(long)(rowb + r) * N + col] = acc[i][j][r] + bv;
    }
  }
  (void)zbf; (void)wnb; (void)shI; (void)EI;
}

// ---------------------------------------------------------------------------
// Expert GEMM (round-5): C_slice[b,n] = sum_{e in slice} wn[b,e]*(z@W_e^T+b_e)
//   BM=64, 4 waves (2x2). z-tile pre-packed in A-fragment layout (zpk) ->
//   loaded ONCE into registers (areg, reused for all experts). Inner loop is
//   pure B-streaming: stage KSTG_ k-subtiles (32KB for big layers) async,
//   2 barriers per KSTG_*16 MFMAs/wave. Per-expert tmp acc initialized with
//   fp32 bias; folded into mainAcc with fp32 wn (row-scale, C-layout rows).
// ---------------------------------------------------------------------------
template <int BN_, int KE_, int KSTG_>
__global__ __launch_bounds__(256, 3) void egemm_k(
    const unsigned short* __restrict__ zpk, const float* __restrict__ wnT,
    const float* __restrict__ bias, const unsigned short* __restrict__ PB,
    float* __restrict__ Cbase, long partStride, int N, int nsubsTot,
    int splits) {
  constexpr int KT2 = KE_ / 32;   // K-subtiles (K=32) per expert
  constexpr int NS = BN_ / 16;
  constexpr int NSTG = KT2 / KSTG_;
  constexpr int TM = 2, TN = NS / 2;  // waves 2x2, WTM=32
  constexpr int MS = 4;               // BM=64
  constexpr int WTN = BN_ / 2;

  __shared__ __align__(16) unsigned short Bs[KSTG_ * NS * 512];

  const int tid = threadIdx.x, lane = tid & 63, wid = tid >> 6;
  const int wrow = wid >> 1, wcol = wid & 1;
  const int mb = blockIdx.x, ntile = blockIdx.y, slice = blockIdx.z;
  const int epb = NEXP / splits, e0 = slice * epb;
  const int n0 = ntile * BN_;
  float* __restrict__ Cp = Cbase + (long)slice * partStride;
  const int nn = lane & 15, q = lane >> 4;

  // Resident A fragments (this block's z tile), loaded once, expert-invariant.
  u32x4 areg[TM][KT2];
  {
    const unsigned short* zb = zpk + (long)mb * (KT2 * MS * 512);
#pragma unroll
    for (int i = 0; i < TM; ++i) {
      const int msub = wrow * TM + i;
#pragma unroll
      for (int kt = 0; kt < KT2; ++kt)
        areg[i][kt] = *(const u32x4*)(zb + (kt * MS + msub) * 512 + lane * 8);
    }
  }

  f32x4 mainAcc[TM][TN] = {};

  for (int ei = 0; ei < epb; ++ei) {
    const int e = e0 + ei;

    float bv[TN];
#pragma unroll
    for (int j = 0; j < TN; ++j)
      bv[j] = bias[(long)e * N + n0 + wcol * WTN + j * 16 + nn];
    f32x4 tmp[TM][TN];
#pragma unroll
    for (int i = 0; i < TM; ++i)
#pragma unroll
      for (int j = 0; j < TN; ++j) {
        f32x4 t = {bv[j], bv[j], bv[j], bv[j]};
        tmp[i][j] = t;
      }

#pragma unroll
    for (int st = 0; st < NSTG; ++st) {
      for (int f = wid; f < KSTG_ * NS; f += 4) {
        const int kloc = f / NS, ns = f % NS;
        const long fragIdx =
            ((long)e * KT2 + st * KSTG_ + kloc) * nsubsTot + (ntile * NS + ns);
        async_copy16(PB + fragIdx * 512 + lane * 8, &Bs[f * 512 + lane * 8]);
      }
      __syncthreads();
#pragma unroll
      for (int kk = 0; kk < KSTG_; ++kk) {
        bf16x8 bfr[TN];
#pragma unroll
        for (int j = 0; j < TN; ++j)
          bfr[j] = __builtin_bit_cast(
              bf16x8,
              *(const u32x4*)&Bs[(kk * NS + wcol * TN + j) * 512 + lane * 8]);
        const int ktloc = st * KSTG_ + kk;
#pragma unroll
        for (int i = 0; i < TM; ++i) {
          bf16x8 af = __builtin_bit_cast(bf16x8, areg[i][ktloc]);
#pragma unroll
          for (int j = 0; j < TN; ++j)
            tmp[i][j] = __builtin_amdgcn_mfma_f32_16x16x32_bf16(
                af, bfr[j], tmp[i][j], 0, 0, 0);
        }
      }
      __syncthreads();
    }

    // mainAcc += wn[:,e] (fp32, per-row) * tmp
#pragma unroll
    for (int i = 0; i < TM; ++i) {
      const int rowb = mb * 64 + wrow * 32 + i * 16 + q * 4;
      f32x4 wn4 = *(const f32x4*)(wnT + (long)e * BATCH + rowb);
#pragma unroll
      for (int j = 0; j < TN; ++j) mainAcc[i][j] += wn4 * tmp[i][j];
    }
  }

#pragma unroll
  for (int i = 0; i < TM; ++i) {
    const int rowb = mb * 64 + wrow * 32 + i * 16 + q * 4;
#pragma unroll
    for (int j = 0; j < TN; ++j) {
      const int col = n0 + wcol * WTN + j * 16 + nn;
#pragma unroll
      for (int r = 0; r < 4; ++r)
        Cp[(long)(rowb + r) * N + col] = mainAcc[i][j][r];
    }
  }
}

// H[idx] = sum over nparts partials, written in place over partial 0.
__global__ void hbuild_k(float* __restrict__ P, long partStride, int nparts,
                         int total4) {
  const int idx = blockIdx.x * 256 + threadIdx.x;
  if (idx >= total4) return;
  f32x4 s = *(const f32x4*)(P + (long)idx * 4);
  for (int p = 1; p < nparts; ++p)
    s += *(const f32x4*)(P + p * partStride + (long)idx * 4);
  *(f32x4*)(P + (long)idx * 4) = s;
}

// BN stats: 4 columns per block, float4 row reads.
__global__ void stats_k(const float* __restrict__ H, int C,
                        const float* __restrict__ g, const float* __restrict__ b,
                        float* __restrict__ scv, float* __restrict__ shv) {
  const int c0 = blockIdx.x * 4;
  f32x4 s = {0.f, 0.f, 0.f, 0.f}, s2 = {0.f, 0.f, 0.f, 0.f};
  for (int r = threadIdx.x; r < BATCH; r += 256) {
    f32x4 x = *(const f32x4*)(H + (long)r * C + c0);
    s += x;
    s2 += x * x;
  }
  __shared__ f32x4 sb[256], qb[256];
  sb[threadIdx.x] = s;
  qb[threadIdx.x] = s2;
  __syncthreads();
  for (int st = 128; st > 0; st >>= 1) {
    if (threadIdx.x < st) {
      sb[threadIdx.x] += sb[threadIdx.x + st];
      qb[threadIdx.x] += qb[threadIdx.x + st];
    }
    __syncthreads();
  }
  if (threadIdx.x < 4) {
    const int c = c0 + threadIdx.x;
    float mu = sb[0][threadIdx.x] * (1.f / BATCH);
    float var = qb[0][threadIdx.x] * (1.f / BATCH) - mu * mu;
    float isig = 1.f / sqrtf(var + 1e-5f);
    float sc_ = g[c] * isig;
    scv[c] = sc_;
    shv[c] = b[c] - mu * sc_;
  }
}

// zpk = packed-A-fragment bf16 of prelu(bn(H)); C=256 fixed.
// chunk c -> (mb = c>>11, kt = (c&2047)>>8, msub = (c>>6)&3, ln = c&63);
// row = mb*64+msub*16+(ln&15), col = kt*32+(ln>>4)*8.
__global__ void zbuild_pk(const float* __restrict__ H,
                          const float* __restrict__ scv,
                          const float* __restrict__ shv,
                          const float* __restrict__ alphaPtr,
                          unsigned short* __restrict__ zpk) {
  const int c = blockIdx.x * 256 + threadIdx.x;  // 131072 total
  const float alpha = alphaPtr[0];
  const int mb = c >> 11, r = c & 2047;
  const int kt = r >> 8, q2 = r & 255;
  const int msub = q2 >> 6, ln = q2 & 63;
  const int row = mb * 64 + msub * 16 + (ln & 15);
  const int col = kt * 32 + (ln >> 4) * 8;
  const float* src = H + (long)row * 256 + col;
  f32x4 a0 = *(const f32x4*)src, a1 = *(const f32x4*)(src + 4);
  f32x4 s0 = *(const f32x4*)(scv + col), s1 = *(const f32x4*)(scv + col + 4);
  f32x4 h0 = *(const f32x4*)(shv + col), h1 = *(const f32x4*)(shv + col + 4);
  u16x8 o;
#pragma unroll
  for (int j = 0; j < 4; ++j) {
    float v = fmaf(a0[j], s0[j], h0[j]);
    v = v >= 0.f ? v : alpha * v;
    o[j] = f2bf(v);
    float v2 = fmaf(a1[j], s1[j], h1[j]);
    v2 = v2 >= 0.f ? v2 : alpha * v2;
    o[4 + j] = f2bf(v2);
  }
  *(u16x8*)(zpk + (long)c * 8) = o;
}

// x0 (fp32 [4096,64]) -> packed-A-fragment bf16 (K=64: 2 kt per mblock).
__global__ void cast_pk(const float* __restrict__ x,
                        unsigned short* __restrict__ zpk) {
  const int c = blockIdx.x * 256 + threadIdx.x;  // 32768 total
  const int mb = c >> 9, r = c & 511;
  const int kt = r >> 8, q2 = r & 255;
  const int msub = q2 >> 6, ln = q2 & 63;
  const int row = mb * 64 + msub * 16 + (ln & 15);
  const int col = kt * 32 + (ln >> 4) * 8;
  const float* src = x + (long)row * 64 + col;
  f32x4 a0 = *(const f32x4*)src, a1 = *(const f32x4*)(src + 4);
  u16x8 o;
#pragma unroll
  for (int j = 0; j < 4; ++j) {
    o[j] = f2bf(a0[j]);
    o[4 + j] = f2bf(a1[j]);
  }
  *(u16x8*)(zpk + (long)c * 8) = o;
}

// w = prelu(bn(G3)) fp32, + global sum (for wn = w/w_sum)
__global__ void wbuild_k(const float* __restrict__ G, const float* __restrict__ scv,
                         const float* __restrict__ shv,
                         const float* __restrict__ alphaPtr,
                         float* __restrict__ w, float* __restrict__ wsum) {
  const int idx = blockIdx.x * 256 + threadIdx.x;  // exactly 65536 threads
  const float alpha = alphaPtr[0];
  const int c0 = (idx * 4) & 63;
  f32x4 x = *(const f32x4*)(G + (long)idx * 4);
  f32x4 sv = *(const f32x4*)(scv + c0);
  f32x4 hv = *(const f32x4*)(shv + c0);
  f32x4 o;
  float part = 0.f;
#pragma unroll
  for (int j = 0; j < 4; ++j) {
    float v = fmaf(x[j], sv[j], hv[j]);
    v = v >= 0.f ? v : alpha * v;
    o[j] = v;
    part += v;
  }
  *(f32x4*)(w + (long)idx * 4) = o;
  __shared__ float sb[256];
  sb[threadIdx.x] = part;
  __syncthreads();
  for (int st = 128; st > 0; st >>= 1) {
    if (threadIdx.x < st) sb[threadIdx.x] += sb[threadIdx.x + st];
    __syncthreads();
  }
  if (threadIdx.x == 0) atomicAdd(wsum, sb[0]);
}

__global__ void inv_k(const float* __restrict__ wsum, float* __restrict__ invp) {
  if (threadIdx.x == 0 && blockIdx.x == 0) invp[0] = 1.0f / wsum[0];
}

// wnT[e][b] = w[b][e] / w_sum  (fp32 transposed table for egemm row-scaling)
__global__ void wntbuild_k(const float* __restrict__ w,
                           const float* __restrict__ invp,
                           float* __restrict__ wnT) {
  const int idx = blockIdx.x * 256 + threadIdx.x;  // 262144
  const int e = idx >> 12, b = idx & 4095;
  wnT[idx] = w[(long)b * NEXP + e] * invp[0];
}

// W[e,o,i] fp32 (+optional bias rows) -> fragment-major bf16
__global__ void prepack_k(const float* __restrict__ W, const float* __restrict__ bias,
                          unsigned short* __restrict__ PB, int O, int shI, int EI,
                          long totalChunks) {
  const long t = (long)blockIdx.x * 256 + threadIdx.x;
  if (t >= totalChunks) return;
  const int lane = (int)(t & 63);
  const long frag = t >> 6;
  const int nsubs = O / 16;
  const int nsub = (int)(frag % nsubs);
  const long ktile = frag / nsubs;
  const int n = nsub * 16 + (lane & 15);
  const int k = (int)(ktile * 32 + (lane >> 4) * 8);
  u16x8 o;
  if (k < EI) {
    const int e = k >> shI;
    const int i0 = k & ((1 << shI) - 1);
    const float* src = W + ((long)e * O + n) * (1 << shI) + i0;
    f32x4 a0 = *(const f32x4*)src;
    f32x4 a1 = *(const f32x4*)(src + 4);
#pragma unroll
    for (int j = 0; j < 4; ++j) {
      o[j] = f2bf(a0[j]);
      o[4 + j] = f2bf(a1[j]);
    }
  } else {
#pragma unroll
    for (int j = 0; j < 8; ++j) {
      const int ee = k + j - EI;
      o[j] = f2bf(bias[(long)ee * O + n]);
    }
  }
  *(u16x8*)(PB + t * 8) = o;
}

__global__ void reduceN_k(const float* __restrict__ P, long partStride, int nparts,
                          float* __restrict__ out, int total4) {
  const int idx = blockIdx.x * 256 + threadIdx.x;
  if (idx >= total4) return;
  f32x4 s = {0.f, 0.f, 0.f, 0.f};
  for (int p = 0; p < nparts; ++p) s += *(const f32x4*)(P + p * partStride + (long)idx * 4);
  *(f32x4*)(out + (long)idx * 4) = s;
}

// ---------------------------------------------------------------------------
extern "C" void kernel_launch(void* const* d_in, const int* in_sizes, int n_in,
                              void* d_out, int out_size, void* d_ws, size_t ws_size,
                              hipStream_t stream) {
  const float* m0 = (const float*)d_in[0];
  const float* x0 = (const float*)d_in[1];
  const float* mW1 = (const float*)d_in[2];
  const float* mb1 = (const float*)d_in[3];
  const float* mg1 = (const float*)d_in[4];
  const float* mbe1 = (const float*)d_in[5];
  const float* ma1 = (const float*)d_in[6];
  const float* mW2 = (const float*)d_in[7];
  const float* mb2 = (const float*)d_in[8];
  const float* mg2 = (const float*)d_in[9];
  const float* mbe2 = (const float*)d_in[10];
  const float* ma2 = (const float*)d_in[11];
  const float* mW3 = (const float*)d_in[12];
  const float* mb3 = (const float*)d_in[13];
  const float* mg3 = (const float*)d_in[14];
  const float* mbe3 = (const float*)d_in[15];
  const float* ma3 = (const float*)d_in[16];
  const float* Wenc0 = (const float*)d_in[17];
  const float* benc0 = (const float*)d_in[18];
  const float* Wenc1 = (const float*)d_in[19];
  const float* benc1 = (const float*)d_in[20];
  const float* Wdec0 = (const float*)d_in[21];
  const float* bdec0 = (const float*)d_in[22];
  const float* Wdec1 = (const float*)d_in[23];
  const float* bdec1 = (const float*)d_in[24];
  const float* bng = (const float*)d_in[25];
  const float* bnb = (const float*)d_in[26];
  const float* aexp = (const float*)d_in[27];

  const bool big = ws_size >= (size_t)52 * 1024 * 1024;
  const int SPL = big ? 8 : 4;    // expert-slices for N=256 layers (1024 blocks)
  const int SPLD = big ? 16 : 8;  // expert-slices for dec1 (N=64)

  char* base = (char*)d_ws;
  size_t off = 0;
  auto alloc = [&](size_t bytes) {
    void* p = base + off;
    off = (off + bytes + 255) & ~(size_t)255;
    return p;
  };
  unsigned short* PB = (unsigned short*)alloc(16448L * 256 * 2);  // 8.4 MB
  float* Pb = (float*)alloc((size_t)SPL * BATCH * 256 * 4);       // partials
  float* P0 = Pb;                      // MNet H1 [4096,256] / H3 [4096,64]
  float* P1 = Pb + (long)BATCH * 256;  // MNet H2 [4096,128]
  unsigned short* zApk = (unsigned short*)alloc(BATCH * 256 * 2);
  unsigned short* zBpk = (unsigned short*)alloc(BATCH * 256 * 2);
  unsigned short* x0pk = (unsigned short*)alloc(BATCH * 64 * 2);
  float* wbuf = (float*)alloc(BATCH * 64 * 4);
  float* wnT = (float*)alloc((size_t)NEXP * BATCH * 4);  // 1 MB
  float* scv = (float*)alloc(256 * 4);
  float* shv = (float*)alloc(256 * 4);
  float* wsum = (float*)alloc(256);
  float* invp = (float*)alloc(256);

  const dim3 blk(256);
  const long PS = BATCH * 256;  // partial stride (elements)

  // ---- MNet L1: H1 = m0 @ mW1^T + mb1 -> P0 [4096,256]
  prepack_k<<<16, blk, 0, stream>>>(mW1, nullptr, PB, 256, 7, 128, 4096);
  gemm_k<64, 128, 2, 2, AM_PLAIN><<<dim3(64, 2, 1), blk, 0, stream>>>(
      m0, nullptr, nullptr, nullptr, nullptr, nullptr, 0, 0, PB, 128, 16,
      P0, 0, mb1, 256, 2, 1);
  stats_k<<<64, blk, 0, stream>>>(P0, 256, mg1, mbe1, scv, shv);

  // ---- MNet L2: H2 = prelu(bn(H1)) @ mW2^T + mb2 -> P1 [4096,128]
  prepack_k<<<16, blk, 0, stream>>>(mW2, nullptr, PB, 128, 8, 256, 4096);
  gemm_k<64, 128, 2, 2, AM_BN><<<dim3(64, 1, 1), blk, 0, stream>>>(
      P0, scv, shv, ma1, nullptr, nullptr, 0, 0, PB, 256, 8, P1, 0, mb2,
      128, 4, 1);
  stats_k<<<32, blk, 0, stream>>>(P1, 128, mg2, mbe2, scv, shv);

  // ---- MNet L3: H3 = prelu(bn(H2)) @ mW3^T + mb3 -> P0 [4096,64]
  prepack_k<<<4, blk, 0, stream>>>(mW3, nullptr, PB, 64, 7, 128, 1024);
  gemm_k<64, 64, 2, 2, AM_BN><<<dim3(64, 1, 1), blk, 0, stream>>>(
      P1, scv, shv, ma2, nullptr, nullptr, 0, 0, PB, 128, 4, P0, 0, mb3,
      64, 2, 1);
  stats_k<<<16, blk, 0, stream>>>(P0, 64, mg3, mbe3, scv, shv);

  // ---- w = prelu(bn(H3)); w_sum; wnT = (w/w_sum)^T; x0 -> packed bf16
  hipMemsetAsync(wsum, 0, 4, stream);
  wbuild_k<<<256, blk, 0, stream>>>(P0, scv, shv, ma3, wbuf, wsum);
  inv_k<<<1, 64, 0, stream>>>(wsum, invp);
  wntbuild_k<<<1024, blk, 0, stream>>>(wbuf, invp, wnT);
  cast_pk<<<128, blk, 0, stream>>>(x0, x0pk);

  // ---- enc0: KE=64 (weights only; bias exact in egemm)
  prepack_k<<<512, blk, 0, stream>>>(Wenc0, nullptr, PB, 256, 6, 4096, 131072);
  egemm_k<128, 64, 2><<<dim3(64, 2, SPL), blk, 0, stream>>>(
      x0pk, wnT, benc0, PB, Pb, PS, 256, 16, SPL);
  hbuild_k<<<1024, blk, 0, stream>>>(Pb, PS, SPL, 262144);
  stats_k<<<64, blk, 0, stream>>>(Pb, 256, bng, bnb, scv, shv);
  zbuild_pk<<<512, blk, 0, stream>>>(Pb, scv, shv, aexp, zApk);

  // ---- enc1: KE=256
  prepack_k<<<2048, blk, 0, stream>>>(Wenc1, nullptr, PB, 256, 8, 16384, 524288);
  egemm_k<128, 256, 4><<<dim3(64, 2, SPL), blk, 0, stream>>>(
      zApk, wnT, benc1, PB, Pb, PS, 256, 16, SPL);
  hbuild_k<<<1024, blk, 0, stream>>>(Pb, PS, SPL, 262144);
  stats_k<<<64, blk, 0, stream>>>(Pb, 256, bng, bnb, scv, shv);
  zbuild_pk<<<512, blk, 0, stream>>>(Pb, scv, shv, aexp, zBpk);

  // ---- dec0
  prepack_k<<<2048, blk, 0, stream>>>(Wdec0, nullptr, PB, 256, 8, 16384, 524288);
  egemm_k<128, 256, 4><<<dim3(64, 2, SPL), blk, 0, stream>>>(
      zBpk, wnT, bdec0, PB, Pb, PS, 256, 16, SPL);
  hbuild_k<<<1024, blk, 0, stream>>>(Pb, PS, SPL, 262144);
  stats_k<<<64, blk, 0, stream>>>(Pb, 256, bng, bnb, scv, shv);
  zbuild_pk<<<512, blk, 0, stream>>>(Pb, scv, shv, aexp, zApk);

  // ---- dec1: N=64, SPLD expert-slices -> partials [4096,64]
  prepack_k<<<512, blk, 0, stream>>>(Wdec1, nullptr, PB, 64, 8, 16384, 131072);
  egemm_k<64, 256, 4><<<dim3(64, 1, SPLD), blk, 0, stream>>>(
      zApk, wnT, bdec1, PB, Pb, (long)BATCH * 64, 64, 4, SPLD);
  reduceN_k<<<256, blk, 0, stream>>>(Pb, (long)BATCH * 64, SPLD, (float*)d_out, 65536);

  (void)in_sizes; (void)n_in; (void)out_size;
}

// Round 6
// 409.153 us; speedup vs baseline: 1.7805x; 1.0226x over previous
//
#include <hip/hip_runtime.h>
#include <stdint.h>

#define BATCH 4096
#define NEXP 64

typedef __bf16 bf16x8 __attribute__((ext_vector_type(8)));
typedef float f32x4 __attribute__((ext_vector_type(4)));
typedef float f32x8 __attribute__((ext_vector_type(8)));
typedef unsigned int u32x4 __attribute__((ext_vector_type(4)));
typedef unsigned short u16x4 __attribute__((ext_vector_type(4)));
typedef unsigned short u16x8 __attribute__((ext_vector_type(8)));

__device__ __forceinline__ unsigned short f2bf(float f) {
  unsigned u = __builtin_bit_cast(unsigned, f);
  u += 0x7fffu + ((u >> 16) & 1u);
  return (unsigned short)(u >> 16);
}
__device__ __forceinline__ float bf2f(unsigned short h) {
  unsigned u = ((unsigned)h) << 16;
  return __builtin_bit_cast(float, u);
}

// async global->LDS, 16B per lane (used only by the MNet GEMM).
__device__ __forceinline__ void async_copy16(const void* g, void* l) {
  __builtin_amdgcn_global_load_lds(
      (const __attribute__((address_space(1))) void*)(uintptr_t)g,
      (__attribute__((address_space(3))) void*)(uintptr_t)l, 16, 0, 0);
}

enum { AM_PLAIN = 0, AM_BN = 1 };

// ---------------------------------------------------------------------------
// MNet GEMM (round-4 structure, AM_PLAIN/AM_BN only).
// ---------------------------------------------------------------------------
template <int BM_, int BN_, int WR, int WC, int AMODE>
__global__ __launch_bounds__(256, 4) void gemm_k(
    const float* __restrict__ Af32, const float* __restrict__ scv,
    const float* __restrict__ shv, const float* __restrict__ alphaPtr,
    const unsigned short* __restrict__ PB, int K, int nsubsTot,
    float* __restrict__ Cp, const float* __restrict__ biasv, int N,
    int ktilesTot) {
  constexpr int MS = BM_ / 16;
  constexpr int NS = BN_ / 16;
  constexpr int WTM = BM_ / WR, WTN = BN_ / WC;
  constexpr int TM = WTM / 16, TN = WTN / 16;
  constexpr int PCH = MS / 2;

  __shared__ __align__(16) unsigned short As[2 * MS * 512];
  __shared__ __align__(16) unsigned short Bs[2 * NS * 512];

  const int tid = threadIdx.x;
  const int lane = tid & 63;
  const int wid = tid >> 6;
  const int wrow = wid / WC, wcol = wid % WC;

  const int m0 = blockIdx.x * BM_;
  const int ntile = blockIdx.y;
  const int n0 = ntile * BN_;

  float alpha = 0.f;
  if constexpr (AMODE == AM_BN) alpha = alphaPtr[0];

  f32x4 acc[TM][TN] = {};

  for (int kt = 0; kt < ktilesTot; ++kt) {
    const int k0 = kt * 64;

    for (int f = wid; f < 2 * NS; f += 4) {
      const int fkt = f / NS, fns = f % NS;
      const long fragIdx = (long)(k0 / 32 + fkt) * nsubsTot + (ntile * NS + fns);
      async_copy16(PB + fragIdx * 512 + lane * 8, &Bs[f * 512 + lane * 8]);
    }

#pragma unroll
    for (int p = 0; p < PCH; ++p) {
      const int id = p * 256 + tid;
      const int fA = id >> 6;
      const int q = id & 63;
      const int ksh = fA / MS, msub = fA % MS;
      const int kq = q >> 4, mrow = q & 15;
      const int m = msub * 16 + mrow;
      const int kg = k0 + ksh * 32 + kq * 8;
      const long mg = m0 + m;
      f32x8 vf;
      if constexpr (AMODE == AM_PLAIN) {
        const f32x4* src = (const f32x4*)(Af32 + mg * K + kg);
        f32x4 a0 = src[0], a1 = src[1];
#pragma unroll
        for (int j = 0; j < 4; ++j) { vf[j] = a0[j]; vf[4 + j] = a1[j]; }
      } else {
        const f32x4* src = (const f32x4*)(Af32 + mg * K + kg);
        f32x4 a0 = src[0], a1 = src[1];
        f32x4 s0 = *(const f32x4*)(scv + kg), s1 = *(const f32x4*)(scv + kg + 4);
        f32x4 h0 = *(const f32x4*)(shv + kg), h1 = *(const f32x4*)(shv + kg + 4);
#pragma unroll
        for (int j = 0; j < 4; ++j) {
          float v = fmaf(a0[j], s0[j], h0[j]);
          vf[j] = v >= 0.f ? v : alpha * v;
          float v2 = fmaf(a1[j], s1[j], h1[j]);
          vf[4 + j] = v2 >= 0.f ? v2 : alpha * v2;
        }
      }
      bf16x8 ob = __builtin_convertvector(vf, bf16x8);
      *(u16x8*)&As[id * 8] = __builtin_bit_cast(u16x8, ob);
    }
    __syncthreads();

#pragma unroll
    for (int ks = 0; ks < 2; ++ks) {
      bf16x8 af[TM], bfr[TN];
#pragma unroll
      for (int i = 0; i < TM; ++i) {
        const int msub = wrow * TM + i;
        af[i] = __builtin_bit_cast(
            bf16x8, *(const u32x4*)&As[(ks * MS + msub) * 512 + lane * 8]);
      }
#pragma unroll
      for (int j = 0; j < TN; ++j) {
        const int nsub = wcol * TN + j;
        bfr[j] = __builtin_bit_cast(
            bf16x8, *(const u32x4*)&Bs[(ks * NS + nsub) * 512 + lane * 8]);
      }
#pragma unroll
      for (int i = 0; i < TM; ++i)
#pragma unroll
        for (int j = 0; j < TN; ++j)
          acc[i][j] = __builtin_amdgcn_mfma_f32_16x16x32_bf16(af[i], bfr[j],
                                                              acc[i][j], 0, 0, 0);
    }
    __syncthreads();
  }

  const int q = lane >> 4, nn = lane & 15;
#pragma unroll
  for (int i = 0; i < TM; ++i) {
    const int rowb = m0 + wrow * WTM + i * 16 + q * 4;
#pragma unroll
    for (int j = 0; j < TN; ++j) {
      const int col = n0 + wcol * WTN + j * 16 + nn;
      const float bv = biasv ? biasv[col] : 0.f;
#pragma unroll
      for (int r = 0; r < 4; ++r)
        Cp[(long)(rowb + r) * N + col] = acc[i][j][r] + bv;
    }
  }
}

// ---------------------------------------------------------------------------
// Expert GEMM (round-6): barrier-free, LDS-free.
//   C_slice[b,n] = sum_{e in slice} wn[b,e]*(z@W_e^T + b_e)
//   Waves 1x4: each of 4 waves owns a disjoint 16*TN-column strip and ALL 64
//   rows (TM=4). A (z tile) resident in VGPRs (loaded once from packed zpk).
//   B fragments stream global->VGPR (buffer_load_dwordx4, 1KB/inst, each
//   fragment read by exactly ONE wave => minimal L2 traffic, no reuse lost).
//   Double-buffered register prefetch; zero __syncthreads in the K-loop.
//   Per-expert fp32 bias init + fp32 wn row-scale fold (exact).
// ---------------------------------------------------------------------------
template <int BN_, int KE_, int EPB>
__global__ __launch_bounds__(256, 2) void egemm_k(
    const unsigned short* __restrict__ zpk, const float* __restrict__ wnT,
    const float* __restrict__ bias, const unsigned short* __restrict__ PB,
    float* __restrict__ Cbase, long partStride, int N, int nsubsTot) {
  constexpr int KT2 = KE_ / 32;  // K-subtiles (K=32) per expert
  constexpr int NS = BN_ / 16;
  constexpr int TN = NS / 4;  // 4 waves split columns
  constexpr int TM = 4;       // BM=64, all rows per wave
  constexpr int MS = 4;

  const int tid = threadIdx.x, lane = tid & 63, wid = tid >> 6;
  const int mb = blockIdx.x, ntile = blockIdx.y, slice = blockIdx.z;
  const int e0 = slice * EPB;
  const int n0 = ntile * BN_;
  float* __restrict__ Cp = Cbase + (long)slice * partStride;
  const int nn = lane & 15, q = lane >> 4;

  // Resident A fragments (expert-invariant).
  u32x4 areg[TM][KT2];
  {
    const unsigned short* zb = zpk + (long)mb * (KT2 * MS * 512);
#pragma unroll
    for (int i = 0; i < TM; ++i)
#pragma unroll
      for (int kt = 0; kt < KT2; ++kt)
        areg[i][kt] = *(const u32x4*)(zb + (kt * MS + i) * 512 + lane * 8);
  }

  // Wave's B-fragment base; fragment (e,kt,j) at + (e*KT2+kt)*kstride + j*512
  const unsigned short* Bw = PB + ((long)ntile * NS + wid * TN) * 512 + lane * 8;
  const long kstride = (long)nsubsTot * 512;

  f32x4 mainAcc[TM][TN] = {};
  u32x4 breg[2][TN];

#pragma unroll
  for (int j = 0; j < TN; ++j)
    breg[0][j] = *(const u32x4*)(Bw + (long)e0 * KT2 * kstride + j * 512);

  for (int ei = 0; ei < EPB; ++ei) {
    const int e = e0 + ei;
    float bv[TN];
#pragma unroll
    for (int j = 0; j < TN; ++j)
      bv[j] = bias[(long)e * N + n0 + wid * (TN * 16) + j * 16 + nn];
    f32x4 tmp[TM][TN];
#pragma unroll
    for (int i = 0; i < TM; ++i)
#pragma unroll
      for (int j = 0; j < TN; ++j) {
        f32x4 t = {bv[j], bv[j], bv[j], bv[j]};
        tmp[i][j] = t;
      }
#pragma unroll
    for (int kt = 0; kt < KT2; ++kt) {
      const int cur = kt & 1, nxt = cur ^ 1;
      if (kt + 1 < KT2 || ei + 1 < EPB) {
        const long tnext = (long)e * KT2 + kt + 1;
#pragma unroll
        for (int j = 0; j < TN; ++j)
          breg[nxt][j] = *(const u32x4*)(Bw + tnext * kstride + j * 512);
      }
#pragma unroll
      for (int i = 0; i < TM; ++i) {
        bf16x8 af = __builtin_bit_cast(bf16x8, areg[i][kt]);
#pragma unroll
        for (int j = 0; j < TN; ++j)
          tmp[i][j] = __builtin_amdgcn_mfma_f32_16x16x32_bf16(
              af, __builtin_bit_cast(bf16x8, breg[cur][j]), tmp[i][j], 0, 0, 0);
      }
    }
    // mainAcc += wn[:,e] (fp32, per-row) * tmp
#pragma unroll
    for (int i = 0; i < TM; ++i) {
      const int rowb = mb * 64 + i * 16 + q * 4;
      f32x4 wn4 = *(const f32x4*)(wnT + (long)e * BATCH + rowb);
#pragma unroll
      for (int j = 0; j < TN; ++j) mainAcc[i][j] += wn4 * tmp[i][j];
    }
  }

#pragma unroll
  for (int i = 0; i < TM; ++i) {
    const int rowb = mb * 64 + i * 16 + q * 4;
#pragma unroll
    for (int j = 0; j < TN; ++j) {
      const int col = n0 + wid * (TN * 16) + j * 16 + nn;
#pragma unroll
      for (int r = 0; r < 4; ++r)
        Cp[(long)(rowb + r) * N + col] = mainAcc[i][j][r];
    }
  }
}

// H[idx] = sum over nparts partials, written in place over partial 0.
__global__ void hbuild_k(float* __restrict__ P, long partStride, int nparts,
                         int total4) {
  const int idx = blockIdx.x * 256 + threadIdx.x;
  if (idx >= total4) return;
  f32x4 s = *(const f32x4*)(P + (long)idx * 4);
  for (int p = 1; p < nparts; ++p)
    s += *(const f32x4*)(P + p * partStride + (long)idx * 4);
  *(f32x4*)(P + (long)idx * 4) = s;
}

// BN stats: 4 columns per block, float4 row reads.
__global__ void stats_k(const float* __restrict__ H, int C,
                        const float* __restrict__ g, const float* __restrict__ b,
                        float* __restrict__ scv, float* __restrict__ shv) {
  const int c0 = blockIdx.x * 4;
  f32x4 s = {0.f, 0.f, 0.f, 0.f}, s2 = {0.f, 0.f, 0.f, 0.f};
  for (int r = threadIdx.x; r < BATCH; r += 256) {
    f32x4 x = *(const f32x4*)(H + (long)r * C + c0);
    s += x;
    s2 += x * x;
  }
  __shared__ f32x4 sb[256], qb[256];
  sb[threadIdx.x] = s;
  qb[threadIdx.x] = s2;
  __syncthreads();
  for (int st = 128; st > 0; st >>= 1) {
    if (threadIdx.x < st) {
      sb[threadIdx.x] += sb[threadIdx.x + st];
      qb[threadIdx.x] += qb[threadIdx.x + st];
    }
    __syncthreads();
  }
  if (threadIdx.x < 4) {
    const int c = c0 + threadIdx.x;
    float mu = sb[0][threadIdx.x] * (1.f / BATCH);
    float var = qb[0][threadIdx.x] * (1.f / BATCH) - mu * mu;
    float isig = 1.f / sqrtf(var + 1e-5f);
    float sc_ = g[c] * isig;
    scv[c] = sc_;
    shv[c] = b[c] - mu * sc_;
  }
}

// zpk = packed-A-fragment bf16 of prelu(bn(H)); C=256 fixed.
__global__ void zbuild_pk(const float* __restrict__ H,
                          const float* __restrict__ scv,
                          const float* __restrict__ shv,
                          const float* __restrict__ alphaPtr,
                          unsigned short* __restrict__ zpk) {
  const int c = blockIdx.x * 256 + threadIdx.x;  // 131072 total
  const float alpha = alphaPtr[0];
  const int mb = c >> 11, r = c & 2047;
  const int kt = r >> 8, q2 = r & 255;
  const int msub = q2 >> 6, ln = q2 & 63;
  const int row = mb * 64 + msub * 16 + (ln & 15);
  const int col = kt * 32 + (ln >> 4) * 8;
  const float* src = H + (long)row * 256 + col;
  f32x4 a0 = *(const f32x4*)src, a1 = *(const f32x4*)(src + 4);
  f32x4 s0 = *(const f32x4*)(scv + col), s1 = *(const f32x4*)(scv + col + 4);
  f32x4 h0 = *(const f32x4*)(shv + col), h1 = *(const f32x4*)(shv + col + 4);
  u16x8 o;
#pragma unroll
  for (int j = 0; j < 4; ++j) {
    float v = fmaf(a0[j], s0[j], h0[j]);
    v = v >= 0.f ? v : alpha * v;
    o[j] = f2bf(v);
    float v2 = fmaf(a1[j], s1[j], h1[j]);
    v2 = v2 >= 0.f ? v2 : alpha * v2;
    o[4 + j] = f2bf(v2);
  }
  *(u16x8*)(zpk + (long)c * 8) = o;
}

// x0 (fp32 [4096,64]) -> packed-A-fragment bf16 (K=64: 2 kt per mblock).
__global__ void cast_pk(const float* __restrict__ x,
                        unsigned short* __restrict__ zpk) {
  const int c = blockIdx.x * 256 + threadIdx.x;  // 32768 total
  const int mb = c >> 9, r = c & 511;
  const int kt = r >> 8, q2 = r & 255;
  const int msub = q2 >> 6, ln = q2 & 63;
  const int row = mb * 64 + msub * 16 + (ln & 15);
  const int col = kt * 32 + (ln >> 4) * 8;
  const float* src = x + (long)row * 64 + col;
  f32x4 a0 = *(const f32x4*)src, a1 = *(const f32x4*)(src + 4);
  u16x8 o;
#pragma unroll
  for (int j = 0; j < 4; ++j) {
    o[j] = f2bf(a0[j]);
    o[4 + j] = f2bf(a1[j]);
  }
  *(u16x8*)(zpk + (long)c * 8) = o;
}

// w = prelu(bn(G3)) fp32, + global sum (for wn = w/w_sum)
__global__ void wbuild_k(const float* __restrict__ G, const float* __restrict__ scv,
                         const float* __restrict__ shv,
                         const float* __restrict__ alphaPtr,
                         float* __restrict__ w, float* __restrict__ wsum) {
  const int idx = blockIdx.x * 256 + threadIdx.x;  // exactly 65536 threads
  const float alpha = alphaPtr[0];
  const int c0 = (idx * 4) & 63;
  f32x4 x = *(const f32x4*)(G + (long)idx * 4);
  f32x4 sv = *(const f32x4*)(scv + c0);
  f32x4 hv = *(const f32x4*)(shv + c0);
  f32x4 o;
  float part = 0.f;
#pragma unroll
  for (int j = 0; j < 4; ++j) {
    float v = fmaf(x[j], sv[j], hv[j]);
    v = v >= 0.f ? v : alpha * v;
    o[j] = v;
    part += v;
  }
  *(f32x4*)(w + (long)idx * 4) = o;
  __shared__ float sb[256];
  sb[threadIdx.x] = part;
  __syncthreads();
  for (int st = 128; st > 0; st >>= 1) {
    if (threadIdx.x < st) sb[threadIdx.x] += sb[threadIdx.x + st];
    __syncthreads();
  }
  if (threadIdx.x == 0) atomicAdd(wsum, sb[0]);
}

__global__ void inv_k(const float* __restrict__ wsum, float* __restrict__ invp) {
  if (threadIdx.x == 0 && blockIdx.x == 0) invp[0] = 1.0f / wsum[0];
}

// wnT[e][b] = w[b][e] / w_sum  (fp32 transposed table for egemm row-scaling)
__global__ void wntbuild_k(const float* __restrict__ w,
                           const float* __restrict__ invp,
                           float* __restrict__ wnT) {
  const int idx = blockIdx.x * 256 + threadIdx.x;  // 262144
  const int e = idx >> 12, b = idx & 4095;
  wnT[idx] = w[(long)b * NEXP + e] * invp[0];
}

// W[e,o,i] fp32 (+optional bias rows) -> fragment-major bf16
__global__ void prepack_k(const float* __restrict__ W, const float* __restrict__ bias,
                          unsigned short* __restrict__ PB, int O, int shI, int EI,
                          long totalChunks) {
  const long t = (long)blockIdx.x * 256 + threadIdx.x;
  if (t >= totalChunks) return;
  const int lane = (int)(t & 63);
  const long frag = t >> 6;
  const int nsubs = O / 16;
  const int nsub = (int)(frag % nsubs);
  const long ktile = frag / nsubs;
  const int n = nsub * 16 + (lane & 15);
  const int k = (int)(ktile * 32 + (lane >> 4) * 8);
  u16x8 o;
  if (k < EI) {
    const int e = k >> shI;
    const int i0 = k & ((1 << shI) - 1);
    const float* src = W + ((long)e * O + n) * (1 << shI) + i0;
    f32x4 a0 = *(const f32x4*)src;
    f32x4 a1 = *(const f32x4*)(src + 4);
#pragma unroll
    for (int j = 0; j < 4; ++j) {
      o[j] = f2bf(a0[j]);
      o[4 + j] = f2bf(a1[j]);
    }
  } else {
#pragma unroll
    for (int j = 0; j < 8; ++j) {
      const int ee = k + j - EI;
      o[j] = f2bf(bias[(long)ee * O + n]);
    }
  }
  *(u16x8*)(PB + t * 8) = o;
}

__global__ void reduceN_k(const float* __restrict__ P, long partStride, int nparts,
                          float* __restrict__ out, int total4) {
  const int idx = blockIdx.x * 256 + threadIdx.x;
  if (idx >= total4) return;
  f32x4 s = {0.f, 0.f, 0.f, 0.f};
  for (int p = 0; p < nparts; ++p) s += *(const f32x4*)(P + p * partStride + (long)idx * 4);
  *(f32x4*)(out + (long)idx * 4) = s;
}

// ---------------------------------------------------------------------------
extern "C" void kernel_launch(void* const* d_in, const int* in_sizes, int n_in,
                              void* d_out, int out_size, void* d_ws, size_t ws_size,
                              hipStream_t stream) {
  const float* m0 = (const float*)d_in[0];
  const float* x0 = (const float*)d_in[1];
  const float* mW1 = (const float*)d_in[2];
  const float* mb1 = (const float*)d_in[3];
  const float* mg1 = (const float*)d_in[4];
  const float* mbe1 = (const float*)d_in[5];
  const float* ma1 = (const float*)d_in[6];
  const float* mW2 = (const float*)d_in[7];
  const float* mb2 = (const float*)d_in[8];
  const float* mg2 = (const float*)d_in[9];
  const float* mbe2 = (const float*)d_in[10];
  const float* ma2 = (const float*)d_in[11];
  const float* mW3 = (const float*)d_in[12];
  const float* mb3 = (const float*)d_in[13];
  const float* mg3 = (const float*)d_in[14];
  const float* mbe3 = (const float*)d_in[15];
  const float* ma3 = (const float*)d_in[16];
  const float* Wenc0 = (const float*)d_in[17];
  const float* benc0 = (const float*)d_in[18];
  const float* Wenc1 = (const float*)d_in[19];
  const float* benc1 = (const float*)d_in[20];
  const float* Wdec0 = (const float*)d_in[21];
  const float* bdec0 = (const float*)d_in[22];
  const float* Wdec1 = (const float*)d_in[23];
  const float* bdec1 = (const float*)d_in[24];
  const float* bng = (const float*)d_in[25];
  const float* bnb = (const float*)d_in[26];
  const float* aexp = (const float*)d_in[27];

  // Expert-slice widths: 4 slices x 16 experts (512 blocks = 2 blocks/CU,
  // 8 waves/CU at ~230 VGPR). dec1: 8 slices x 8 experts.
  const int SPL = 4, SPLD = 8;

  char* base = (char*)d_ws;
  size_t off = 0;
  auto alloc = [&](size_t bytes) {
    void* p = base + off;
    off = (off + bytes + 255) & ~(size_t)255;
    return p;
  };
  unsigned short* PB = (unsigned short*)alloc(16448L * 256 * 2);  // 8.4 MB
  float* Pb = (float*)alloc((size_t)SPL * BATCH * 256 * 4);       // 16 MB partials
  float* P0 = Pb;                      // MNet H1 [4096,256] / H3 [4096,64]
  float* P1 = Pb + (long)BATCH * 256;  // MNet H2 [4096,128]
  unsigned short* zApk = (unsigned short*)alloc(BATCH * 256 * 2);
  unsigned short* zBpk = (unsigned short*)alloc(BATCH * 256 * 2);
  unsigned short* x0pk = (unsigned short*)alloc(BATCH * 64 * 2);
  float* wbuf = (float*)alloc(BATCH * 64 * 4);
  float* wnT = (float*)alloc((size_t)NEXP * BATCH * 4);  // 1 MB
  float* scv = (float*)alloc(256 * 4);
  float* shv = (float*)alloc(256 * 4);
  float* wsum = (float*)alloc(256);
  float* invp = (float*)alloc(256);

  const dim3 blk(256);
  const long PS = BATCH * 256;  // partial stride (elements)

  // ---- MNet L1: H1 = m0 @ mW1^T + mb1 -> P0 [4096,256]
  prepack_k<<<16, blk, 0, stream>>>(mW1, nullptr, PB, 256, 7, 128, 4096);
  gemm_k<64, 128, 2, 2, AM_PLAIN><<<dim3(64, 2, 1), blk, 0, stream>>>(
      m0, nullptr, nullptr, nullptr, PB, 128, 16, P0, mb1, 256, 2);
  stats_k<<<64, blk, 0, stream>>>(P0, 256, mg1, mbe1, scv, shv);

  // ---- MNet L2: H2 = prelu(bn(H1)) @ mW2^T + mb2 -> P1 [4096,128]
  prepack_k<<<16, blk, 0, stream>>>(mW2, nullptr, PB, 128, 8, 256, 4096);
  gemm_k<64, 128, 2, 2, AM_BN><<<dim3(64, 1, 1), blk, 0, stream>>>(
      P0, scv, shv, ma1, PB, 256, 8, P1, mb2, 128, 4);
  stats_k<<<32, blk, 0, stream>>>(P1, 128, mg2, mbe2, scv, shv);

  // ---- MNet L3: H3 = prelu(bn(H2)) @ mW3^T + mb3 -> P0 [4096,64]
  prepack_k<<<4, blk, 0, stream>>>(mW3, nullptr, PB, 64, 7, 128, 1024);
  gemm_k<64, 64, 2, 2, AM_BN><<<dim3(64, 1, 1), blk, 0, stream>>>(
      P1, scv, shv, ma2, PB, 128, 4, P0, mb3, 64, 2);
  stats_k<<<16, blk, 0, stream>>>(P0, 64, mg3, mbe3, scv, shv);

  // ---- w = prelu(bn(H3)); w_sum; wnT = (w/w_sum)^T; x0 -> packed bf16
  hipMemsetAsync(wsum, 0, 4, stream);
  wbuild_k<<<256, blk, 0, stream>>>(P0, scv, shv, ma3, wbuf, wsum);
  inv_k<<<1, 64, 0, stream>>>(wsum, invp);
  wntbuild_k<<<1024, blk, 0, stream>>>(wbuf, invp, wnT);
  cast_pk<<<128, blk, 0, stream>>>(x0, x0pk);

  // ---- enc0: KE=64
  prepack_k<<<512, blk, 0, stream>>>(Wenc0, nullptr, PB, 256, 6, 4096, 131072);
  egemm_k<128, 64, 16><<<dim3(64, 2, SPL), blk, 0, stream>>>(
      x0pk, wnT, benc0, PB, Pb, PS, 256, 16);
  hbuild_k<<<1024, blk, 0, stream>>>(Pb, PS, SPL, 262144);
  stats_k<<<64, blk, 0, stream>>>(Pb, 256, bng, bnb, scv, shv);
  zbuild_pk<<<512, blk, 0, stream>>>(Pb, scv, shv, aexp, zApk);

  // ---- enc1: KE=256
  prepack_k<<<2048, blk, 0, stream>>>(Wenc1, nullptr, PB, 256, 8, 16384, 524288);
  egemm_k<128, 256, 16><<<dim3(64, 2, SPL), blk, 0, stream>>>(
      zApk, wnT, benc1, PB, Pb, PS, 256, 16);
  hbuild_k<<<1024, blk, 0, stream>>>(Pb, PS, SPL, 262144);
  stats_k<<<64, blk, 0, stream>>>(Pb, 256, bng, bnb, scv, shv);
  zbuild_pk<<<512, blk, 0, stream>>>(Pb, scv, shv, aexp, zBpk);

  // ---- dec0
  prepack_k<<<2048, blk, 0, stream>>>(Wdec0, nullptr, PB, 256, 8, 16384, 524288);
  egemm_k<128, 256, 16><<<dim3(64, 2, SPL), blk, 0, stream>>>(
      zBpk, wnT, bdec0, PB, Pb, PS, 256, 16);
  hbuild_k<<<1024, blk, 0, stream>>>(Pb, PS, SPL, 262144);
  stats_k<<<64, blk, 0, stream>>>(Pb, 256, bng, bnb, scv, shv);
  zbuild_pk<<<512, blk, 0, stream>>>(Pb, scv, shv, aexp, zApk);

  // ---- dec1: N=64, 8 expert-slices -> partials [4096,64]
  prepack_k<<<512, blk, 0, stream>>>(Wdec1, nullptr, PB, 64, 8, 16384, 131072);
  egemm_k<64, 256, 8><<<dim3(64, 1, SPLD), blk, 0, stream>>>(
      zApk, wnT, bdec1, PB, Pb, (long)BATCH * 64, 64, 4);
  reduceN_k<<<256, blk, 0, stream>>>(Pb, (long)BATCH * 64, SPLD, (float*)d_out, 65536);

  (void)in_sizes; (void)n_in; (void)out_size; (void)ws_size;
}